// Round 3
// baseline (1860.206 us; speedup 1.0000x reference)
//
#include <hip/hip_runtime.h>
#include <cstdint>

#define BB 16
#define DD 256
#define TT 2048
#define KK 8192
#define NN 32768            // BB*TT
#define QQ 8388608          // BB*DD*TT
typedef unsigned long long u64;

typedef __attribute__((ext_vector_type(8))) short short8;   // 8 bf16 (4 VGPRs)
typedef __attribute__((ext_vector_type(4))) float f32x4;    // MFMA C/D

__device__ __forceinline__ unsigned mapf(float f) {
    unsigned u = __float_as_uint(f);
    return (u & 0x80000000u) ? ~u : (u | 0x80000000u);
}
__device__ __forceinline__ float unmapf(unsigned u) {
    return __uint_as_float((u & 0x80000000u) ? (u & 0x7FFFFFFFu) : ~u);
}
__device__ __forceinline__ unsigned bf16_rne(float v) {
    unsigned ui = __float_as_uint(v);
    return (ui + 0x7FFFu + ((ui >> 16) & 1)) >> 16;
}

// ---------------------------------------------------------------------------
// A32[n] = fp32(fp64 sum of z_n^2); zero cnt & loss. grid 512 x 256
// ---------------------------------------------------------------------------
__global__ __launch_bounds__(256) void k_prepA(const float* __restrict__ z,
                                               float* __restrict__ A32,
                                               int* __restrict__ cnt,
                                               float* __restrict__ out) {
    __shared__ double sd[256];
    int tid = threadIdx.x;
    int r = tid & 63;               // row within block (coalesced over t)
    int c = tid >> 6;               // wave -> d quarter
    int n = blockIdx.x * 64 + r;
    if (blockIdx.x == 0 && tid == 0) { *cnt = 0; out[QQ] = 0.0f; }
    int b = n >> 11, t = n & 2047;
    const float* zp = z + (size_t)b * 524288 + t;
    double s = 0.0;
#pragma unroll 8
    for (int i = 0; i < 64; i++) {
        float v = zp[(size_t)(c * 64 + i) * 2048];
        s = fma((double)v, (double)v, s);
    }
    sd[tid] = s;
    __syncthreads();
    if (c == 0) {
        double tot = sd[r] + sd[64 + r] + sd[128 + r] + sd[192 + r];
        A32[n] = (float)tot;
    }
}

// ---------------------------------------------------------------------------
// z [b][d][t] fp32 -> zh/zl [n][d] bf16 hi/lo, 16B stores. grid 2048 x 256
// ---------------------------------------------------------------------------
__global__ __launch_bounds__(256) void k_convZ(const float* __restrict__ z,
                                               unsigned short* __restrict__ zh,
                                               unsigned short* __restrict__ zl) {
    __shared__ float sm[64][65];
    int tid = threadIdx.x;
    int bid = blockIdx.x;
    int b  = bid >> 7;
    int dt = (bid >> 5) & 3;
    int tt = bid & 31;
    const float* zp = z + (size_t)b * 524288 + (size_t)dt * 131072 + tt * 64;
#pragma unroll
    for (int i = 0; i < 16; i++) {
        int idx = tid + 256 * i;
        int d = idx >> 6, t = idx & 63;
        sm[d][t] = zp[(size_t)d * 2048 + t];
    }
    __syncthreads();
    int d0 = (tid & 7) * 8;
#pragma unroll
    for (int i = 0; i < 2; i++) {
        int t = (tid >> 3) + 32 * i;
        size_t o = ((size_t)(b * 2048 + tt * 64 + t)) * 256 + dt * 64 + d0;
        short8 hv, lv;
#pragma unroll
        for (int j = 0; j < 8; j++) {
            float v = sm[d0 + j][t];
            unsigned hb = bf16_rne(v);
            float hf = __uint_as_float(hb << 16);
            unsigned lb = bf16_rne(v - hf);
            hv[j] = (short)hb;
            lv[j] = (short)lb;
        }
        *(short8*)(zh + o) = hv;
        *(short8*)(zl + o) = lv;
    }
}

// ---------------------------------------------------------------------------
// emb [k][d] fp32 -> eh/el bf16 hi/lo. grid 1024 x 256
// ---------------------------------------------------------------------------
__global__ __launch_bounds__(256) void k_convE(const float* __restrict__ emb,
                                               unsigned short* __restrict__ eh,
                                               unsigned short* __restrict__ el) {
    int base = (blockIdx.x * 256 + threadIdx.x) * 8;
    float4 v0 = *(const float4*)(emb + base);
    float4 v1 = *(const float4*)(emb + base + 4);
    float vv[8] = {v0.x, v0.y, v0.z, v0.w, v1.x, v1.y, v1.z, v1.w};
    short8 hv, lv;
#pragma unroll
    for (int i = 0; i < 8; i++) {
        unsigned hb = bf16_rne(vv[i]);
        float hf = __uint_as_float(hb << 16);
        unsigned lb = bf16_rne(vv[i] - hf);
        hv[i] = (short)hb;
        lv[i] = (short)lb;
    }
    *(short8*)(eh + base) = hv;
    *(short8*)(el + base) = lv;
}

// ---------------------------------------------------------------------------
// MFMA distance GEMM v5: score = -2*(zh.eh + zh.el + zl.eh)
// NO LDS, NO barriers, NO manual waitcnt. Each wave independently streams
// MFMA fragments straight from global (L2-resident: B slab 1MB/ng, A 128KB/mt)
// using the per-lane fragment layout (row=lane&15, chunk=lane>>4) = one
// global_load_dwordx4 per fragment. Wave tile 32 rows x 128 codes (2 mi x
// 8 ni), so no cross-wave sharing; top-2 state halves to 32 VGPRs ->
// __launch_bounds__(256,3) = 3 blocks/CU = 12 waves. XCD-affine: ng = bid&7
// (each XCD owns one ng's B slab). Per-acc MFMA chain order identical to v4
// -> bit-identical scores -> select/refine contract unchanged.
// grid 2048 (ng=bid&7, mt=bid>>3).
// ---------------------------------------------------------------------------
__global__ __launch_bounds__(256, 3) void k_gemm(const unsigned short* __restrict__ zh,
                                                 const unsigned short* __restrict__ zl,
                                                 const unsigned short* __restrict__ eh,
                                                 const unsigned short* __restrict__ el,
                                                 u64* __restrict__ cand) {
    int tid  = threadIdx.x;
    int w    = tid >> 6;
    int lane = tid & 63;
    int lm   = lane & 15;
    int q    = lane >> 4;

    int bid = blockIdx.x;
    int ng  = bid & 7;              // XCD-affine slab: XCD x works on ng = x
    int mt  = bid >> 3;

    // per-lane offset within a 16-row fragment panel (shorts):
    // row = lane&15 (stride 256 shorts), k-chunk = lane>>4 (8 shorts each)
    int lofs = lm * 256 + q * 8;

    const unsigned short* Ah = zh + (size_t)(mt * 128 + w * 32) * 256 + lofs;
    const unsigned short* Al = zl + (size_t)(mt * 128 + w * 32) * 256 + lofs;
    const unsigned short* Bh = eh + (size_t)(ng * 1024) * 256 + lofs;
    const unsigned short* Bl = el + (size_t)(ng * 1024) * 256 + lofs;

    // float-domain top-2 per (mi,reg): track MAX of acc (score = -2*acc).
    float v1a[2][4], v2a[2][4];
    int   i1a[2][4], i2a[2][4];
#pragma unroll
    for (int mi = 0; mi < 2; mi++)
#pragma unroll
        for (int reg = 0; reg < 4; reg++) {
            v1a[mi][reg] = -3.4e38f; v2a[mi][reg] = -3.4e38f;
            i1a[mi][reg] = 0;        i2a[mi][reg] = 0;
        }

    f32x4 acc[2][8];

    for (int it = 0; it < 64; ++it) {
        int ns   = it >> 3;          // slab (128 codes)
        int kc   = it & 7;           // K-step within slab
        int koff = kc * 32;          // shorts

        if (kc == 0) {
#pragma unroll
            for (int mi = 0; mi < 2; mi++)
#pragma unroll
                for (int ni = 0; ni < 8; ni++) acc[mi][ni] = (f32x4){0.f, 0.f, 0.f, 0.f};
        }

        // A fragments: rows w*32 + mi*16 (+16 rows = +4096 shorts)
        short8 fah0 = *(const short8*)(Ah + koff);
        short8 fah1 = *(const short8*)(Ah + 4096 + koff);
        short8 fal0 = *(const short8*)(Al + koff);
        short8 fal1 = *(const short8*)(Al + 4096 + koff);

        const unsigned short* bhp = Bh + ns * 32768 + koff;
        const unsigned short* blp = Bl + ns * 32768 + koff;

#pragma unroll
        for (int ni = 0; ni < 8; ni++) {
            short8 bh = *(const short8*)(bhp + ni * 4096);
            short8 bl = *(const short8*)(blp + ni * 4096);
            acc[0][ni] = __builtin_amdgcn_mfma_f32_16x16x32_bf16(fah0, bh, acc[0][ni], 0, 0, 0);
            acc[0][ni] = __builtin_amdgcn_mfma_f32_16x16x32_bf16(fal0, bh, acc[0][ni], 0, 0, 0);
            acc[0][ni] = __builtin_amdgcn_mfma_f32_16x16x32_bf16(fah0, bl, acc[0][ni], 0, 0, 0);
            acc[1][ni] = __builtin_amdgcn_mfma_f32_16x16x32_bf16(fah1, bh, acc[1][ni], 0, 0, 0);
            acc[1][ni] = __builtin_amdgcn_mfma_f32_16x16x32_bf16(fal1, bh, acc[1][ni], 0, 0, 0);
            acc[1][ni] = __builtin_amdgcn_mfma_f32_16x16x32_bf16(fah1, bl, acc[1][ni], 0, 0, 0);
        }

        if (kc == 7) {   // slab complete: fold into per-lane top-2
            int idb = ng * 1024 + ns * 128 + lm;
#pragma unroll
            for (int ni = 0; ni < 8; ni++) {
                int id = idb + ni * 16;
#pragma unroll
                for (int mi = 0; mi < 2; mi++)
#pragma unroll
                    for (int reg = 0; reg < 4; reg++) {
                        float v = acc[mi][ni][reg];
                        bool c2 = v > v2a[mi][reg];
                        bool c1 = v > v1a[mi][reg];
                        v2a[mi][reg] = c2 ? v  : v2a[mi][reg];
                        i2a[mi][reg] = c2 ? id : i2a[mi][reg];
                        v2a[mi][reg] = c1 ? v1a[mi][reg] : v2a[mi][reg];
                        i2a[mi][reg] = c1 ? i1a[mi][reg] : i2a[mi][reg];
                        v1a[mi][reg] = c1 ? v  : v1a[mi][reg];
                        i1a[mi][reg] = c1 ? id : i1a[mi][reg];
                    }
            }
        }
    }

    // pack to mapf-u64, butterfly across the 16 lm-lanes (bits 0..3 of lane);
    // each wave owns 32 distinct rows -> write cand directly (no LDS merge).
#pragma unroll
    for (int mi = 0; mi < 2; mi++)
#pragma unroll
        for (int reg = 0; reg < 4; reg++) {
            float s1 = -2.0f * v1a[mi][reg];
            float s2 = -2.0f * v2a[mi][reg];
            u64 p1 = ((u64)mapf(s1) << 32) | (unsigned)i1a[mi][reg];
            u64 p2 = ((u64)mapf(s2) << 32) | (unsigned)i2a[mi][reg];
#pragma unroll
            for (int msk = 1; msk <= 8; msk <<= 1) {
                u64 q1 = __shfl_xor(p1, msk, 64);
                u64 q2 = __shfl_xor(p2, msk, 64);
                u64 n1 = (p1 < q1) ? p1 : q1;
                u64 hi = (p1 < q1) ? q1 : p1;
                u64 n2 = (q2 < p2) ? q2 : p2;
                n2 = (hi < n2) ? hi : n2;
                p1 = n1; p2 = n2;
            }
            if (lm == 0) {
                int m = mt * 128 + w * 32 + mi * 16 + q * 4 + reg;  // global row
                size_t o = ((size_t)ng * 32768 + m) * 2;
                cand[o]     = p1;
                cand[o + 1] = p2;
            }
        }
}

// ---------------------------------------------------------------------------
// select (MFMA path): merge 8 (top1,top2) pairs; commit or flag. grid 128
// ---------------------------------------------------------------------------
__global__ __launch_bounds__(256) void k_select(const u64* __restrict__ cand,
                                                const float* __restrict__ A32,
                                                int* __restrict__ keys,
                                                int* __restrict__ cnt,
                                                int* __restrict__ list) {
    int n = blockIdx.x * 256 + threadIdx.x;
    u64 m1 = cand[(size_t)n * 2];
    u64 m2 = cand[(size_t)n * 2 + 1];
#pragma unroll
    for (int j = 1; j < 8; j++) {
        u64 c1 = cand[((size_t)j * 32768 + n) * 2];
        u64 c2 = cand[((size_t)j * 32768 + n) * 2 + 1];
        if (c1 < m1) { m2 = (m1 < m2) ? m1 : m2; m1 = c1; }
        else         { m2 = (c1 < m2) ? c1 : m2; }
        m2 = (c2 < m2) ? c2 : m2;
    }
    keys[n] = (int)(unsigned)(m1 & 0xFFFFFFFFull);
    float f1 = unmapf((unsigned)(m1 >> 32));
    float f2 = unmapf((unsigned)(m2 >> 32));
    float W = ((A32[n] >= 255.9f) ? 3.4e-5f : 1.8e-5f) + 4e-6f;  // + 2*eps(bf16x3)
    if (f2 - f1 <= W) {
        int p = atomicAdd(cnt, 1);
        list[p] = n;
    }
}

// ---------------------------------------------------------------------------
// FALLBACK path (round-3 proven): fp32 VALU GEMM argmin + its select
// ---------------------------------------------------------------------------
__global__ __launch_bounds__(256) void k_argmin_fb(const float* __restrict__ z,
                                                   const float* __restrict__ emb,
                                                   u64* __restrict__ cand2) {
    __shared__ __align__(16) float smem[8192];
    float* As = smem;
    float* Bs = smem + 4096;

    int tid = threadIdx.x;
    int tx  = tid & 15;
    int ty  = tid >> 4;
    int mt  = blockIdx.x;
    int kh  = blockIdx.y;

    int bimg = mt >> 4;
    int t0   = (mt & 15) << 7;
    const float* zb = z + (size_t)bimg * (DD * TT) + t0;

    float bestv[8], bestv2[8];
    int   besti[8];
#pragma unroll
    for (int i = 0; i < 8; i++) { bestv[i] = 3.4e38f; bestv2[i] = 3.4e38f; besti[i] = 0; }

    int qa = tid & 31, ra = tid >> 5;
    int jb = tid >> 3, db = tid & 7;
    int swz_t = (tx & 7) << 2;

    for (int kc = 0; kc < 32; kc++) {
        int k0 = kh * 4096 + kc * 128;
        float acc[8][8];
#pragma unroll
        for (int i = 0; i < 8; i++)
#pragma unroll
            for (int j = 0; j < 8; j++) acc[i][j] = 0.0f;

        for (int dc = 0; dc < 8; dc++) {
            int d0 = dc * 32;
            __syncthreads();
#pragma unroll
            for (int s = 0; s < 4; s++) {
                int d = ra + 8 * s;
                float4 v = *(const float4*)(zb + (size_t)(d0 + d) * TT + 4 * qa);
                *(float4*)(As + d * 128 + 4 * qa) = v;
            }
#pragma unroll
            for (int s = 0; s < 4; s++) {
                int row = jb + 32 * s;
                float4 v = *(const float4*)(emb + (size_t)(k0 + row) * DD + d0 + 4 * db);
                int col  = (4 * db) ^ ((row & 7) << 2);
                *(float4*)(Bs + row * 32 + col) = v;
            }
            __syncthreads();
#pragma unroll
            for (int g = 0; g < 8; g++) {
                float4 bf[8];
#pragma unroll
                for (int in = 0; in < 8; in++) {
                    int nn = in * 16 + tx;
                    bf[in] = *(const float4*)(Bs + nn * 32 + ((4 * g) ^ swz_t));
                }
#pragma unroll
                for (int j = 0; j < 4; j++) {
                    int d = 4 * g + j;
                    float4 a0 = *(const float4*)(As + d * 128 + ty * 8);
                    float4 a1 = *(const float4*)(As + d * 128 + ty * 8 + 4);
                    float av[8] = {a0.x, a0.y, a0.z, a0.w, a1.x, a1.y, a1.z, a1.w};
#pragma unroll
                    for (int im = 0; im < 8; im++) {
#pragma unroll
                        for (int in = 0; in < 8; in++) {
                            const float* bfp = (const float*)&bf[in];
                            acc[im][in] = fmaf(av[im], bfp[j], acc[im][in]);
                        }
                    }
                }
            }
        }
#pragma unroll
        for (int in = 0; in < 8; in++) {
            int k = k0 + in * 16 + tx;
#pragma unroll
            for (int im = 0; im < 8; im++) {
                float s = -2.0f * acc[im][in];
                if (s < bestv[im]) { bestv2[im] = bestv[im]; bestv[im] = s; besti[im] = k; }
                else if (s < bestv2[im]) { bestv2[im] = s; }
            }
        }
    }

    __syncthreads();
    u64* red = (u64*)smem;
#pragma unroll
    for (int im = 0; im < 8; im++) {
        int r = ty * 8 + im;
        red[r * 32 + tx * 2 + 0] = ((u64)mapf(bestv[im]) << 32) | (unsigned)besti[im];
        red[r * 32 + tx * 2 + 1] = ((u64)mapf(bestv2[im]) << 32);
    }
    __syncthreads();
    if (tid < 128) {
        const u64* base = red + tid * 32;
        u64 p1 = base[0];
        u64 s2 = base[1];
#pragma unroll
        for (int t = 1; t < 16; t++) {
            u64 c1 = base[t * 2], c2 = base[t * 2 + 1];
            if (c1 < p1) { s2 = (p1 < s2) ? p1 : s2; p1 = c1; }
            else         { s2 = (c1 < s2) ? c1 : s2; }
            s2 = (c2 < s2) ? c2 : s2;
        }
        int n = mt * 128 + tid;
        cand2[(size_t)n * 4 + kh * 2]     = p1;
        cand2[(size_t)n * 4 + kh * 2 + 1] = s2;
    }
}

__global__ __launch_bounds__(256) void k_select_fb(const u64* __restrict__ cand2,
                                                   const float* __restrict__ A32,
                                                   int* __restrict__ keys,
                                                   int* __restrict__ cnt,
                                                   int* __restrict__ list) {
    int n = blockIdx.x * 256 + threadIdx.x;
    u64 a1 = cand2[(size_t)n * 4 + 0], a2 = cand2[(size_t)n * 4 + 1];
    u64 b1 = cand2[(size_t)n * 4 + 2], b2 = cand2[(size_t)n * 4 + 3];
    u64 m1 = (a1 < b1) ? a1 : b1;
    u64 lo = (a1 < b1) ? b1 : a1;
    u64 m2 = (a2 < b2) ? a2 : b2;
    m2 = (lo < m2) ? lo : m2;

    keys[n] = (int)(unsigned)(m1 & 0xFFFFFFFFull);
    float f1 = unmapf((unsigned)(m1 >> 32));
    float f2 = unmapf((unsigned)(m2 >> 32));
    float W = (A32[n] >= 255.9f) ? 3.4e-5f : 1.8e-5f;
    if (f2 - f1 <= W) {
        int p = atomicAdd(cnt, 1);
        list[p] = n;
    }
}

// ---------------------------------------------------------------------------
// exact np-fp32 emulation for flagged rows (round-3 proven). grid 512
// ---------------------------------------------------------------------------
__global__ __launch_bounds__(256) void k_refine(const float* __restrict__ z,
                                                const float* __restrict__ emb,
                                                const float* __restrict__ A32,
                                                const int* __restrict__ list,
                                                const int* __restrict__ cnt,
                                                int* __restrict__ keys) {
    __shared__ __align__(16) float zs[256][8];
    __shared__ float aA[8];
    __shared__ int   ln[8];
    __shared__ u64   wred[4 * 8];

    int tid = threadIdx.x, lane = tid & 63, w = tid >> 6;
    int count = *cnt;
    int ngroups = (count + 7) >> 3;

    for (int g = blockIdx.x; g < ngroups; g += gridDim.x) {
        __syncthreads();
#pragma unroll
        for (int r = 0; r < 8; r++) {
            int row = g * 8 + r;
            int n   = list[(row < count) ? row : 0];
            int b = n >> 11, t = n & 2047;
            zs[tid][r] = z[(size_t)b * (DD * TT) + (size_t)tid * TT + t];
            if (tid == 0) { ln[r] = (row < count) ? n : -1; aA[r] = A32[n]; }
        }
        __syncthreads();

        u64 best[8];
#pragma unroll
        for (int r = 0; r < 8; r++) best[r] = 0xFFFFFFFFFFFFFFFFull;

        float Ar[8];
#pragma unroll
        for (int r = 0; r < 8; r++) Ar[r] = aA[r];

        for (int c = 0; c < 8; c++) {
            int kbase = c * 1024 + tid;
            const float4* e0 = (const float4*)(emb + (size_t)(kbase)       * DD);
            const float4* e1 = (const float4*)(emb + (size_t)(kbase + 256) * DD);
            const float4* e2 = (const float4*)(emb + (size_t)(kbase + 512) * DD);
            const float4* e3 = (const float4*)(emb + (size_t)(kbase + 768) * DD);
            float acc[4][8];
#pragma unroll
            for (int qq = 0; qq < 4; qq++)
#pragma unroll
                for (int r = 0; r < 8; r++) acc[qq][r] = 0.0f;

            for (int d4 = 0; d4 < 64; d4++) {
                float4 v0 = e0[d4], v1 = e1[d4], v2 = e2[d4], v3 = e3[d4];
                const float* p0 = (const float*)&v0;
                const float* p1 = (const float*)&v1;
                const float* p2 = (const float*)&v2;
                const float* p3 = (const float*)&v3;
#pragma unroll
                for (int i = 0; i < 4; i++) {
                    int d = 4 * d4 + i;
                    float4 za = *(const float4*)&zs[d][0];
                    float4 zb2 = *(const float4*)&zs[d][4];
                    const float* zr  = (const float*)&za;
                    const float* zr2 = (const float*)&zb2;
#pragma unroll
                    for (int r = 0; r < 4; r++) {
                        acc[0][r]     = fmaf(zr[r],  p0[i], acc[0][r]);
                        acc[1][r]     = fmaf(zr[r],  p1[i], acc[1][r]);
                        acc[2][r]     = fmaf(zr[r],  p2[i], acc[2][r]);
                        acc[3][r]     = fmaf(zr[r],  p3[i], acc[3][r]);
                        acc[0][r + 4] = fmaf(zr2[r], p0[i], acc[0][r + 4]);
                        acc[1][r + 4] = fmaf(zr2[r], p1[i], acc[1][r + 4]);
                        acc[2][r + 4] = fmaf(zr2[r], p2[i], acc[2][r + 4]);
                        acc[3][r + 4] = fmaf(zr2[r], p3[i], acc[3][r + 4]);
                    }
                }
            }
#pragma unroll
            for (int qq = 0; qq < 4; qq++) {
                int k = kbase + qq * 256;
#pragma unroll
                for (int r = 0; r < 8; r++) {
                    float dk = Ar[r] - 2.0f * acc[qq][r];
                    u64 p = ((u64)mapf(dk) << 32) | (unsigned)k;
                    best[r] = (p < best[r]) ? p : best[r];
                }
            }
        }
#pragma unroll
        for (int r = 0; r < 8; r++) {
            u64 v = best[r];
            for (int off = 32; off; off >>= 1) {
                u64 o = __shfl_down(v, off, 64);
                v = (o < v) ? o : v;
            }
            if (lane == 0) wred[w * 8 + r] = v;
        }
        __syncthreads();
        if (tid < 8) {
            u64 v = wred[tid];
#pragma unroll
            for (int j = 1; j < 4; j++) {
                u64 o = wred[j * 8 + tid];
                v = (o < v) ? o : v;
            }
            int n = ln[tid];
            if (n >= 0) keys[n] = (int)(unsigned)(v & 0xFFFFFFFFull);
        }
        __syncthreads();
    }
}

// ---------------------------------------------------------------------------
// gather quantized, write outputs, loss = 1.25 * mean((q - z)^2)
// ---------------------------------------------------------------------------
__global__ __launch_bounds__(256) void k_out(const float* __restrict__ z,
                                             const float* __restrict__ emb,
                                             const int* __restrict__ keys,
                                             float* __restrict__ out) {
    int tid = threadIdx.x;
    int n   = blockIdx.x * 256 + tid;
    int b   = n >> 11;
    int t   = n & 2047;
    int idx = keys[n];
    out[QQ + 1 + n] = (float)idx;

    const float4* erow = (const float4*)(emb + (size_t)idx * DD);
    const float*  zp   = z   + (size_t)b * (DD * TT) + t;
    float*        op   = out + (size_t)b * (DD * TT) + t;

    float ssd = 0.0f;
#pragma unroll 4
    for (int d4 = 0; d4 < 64; d4++) {
        float4 qv = erow[d4];
        float qa[4] = {qv.x, qv.y, qv.z, qv.w};
#pragma unroll
        for (int r = 0; r < 4; r++) {
            int d = 4 * d4 + r;
            float zv = zp[(size_t)d * TT];
            float df = qa[r] - zv;
            ssd = fmaf(df, df, ssd);
            op[(size_t)d * TT] = qa[r];
        }
    }
    for (int off = 32; off; off >>= 1) ssd += __shfl_down(ssd, off, 64);
    __shared__ float red[4];
    if ((tid & 63) == 0) red[tid >> 6] = ssd;
    __syncthreads();
    if (tid == 0) {
        float tot = red[0] + red[1] + red[2] + red[3];
        atomicAdd(out + QQ, tot * (1.25f / (float)QQ));
    }
}

// ---------------------------------------------------------------------------
extern "C" void kernel_launch(void* const* d_in, const int* in_sizes, int n_in,
                              void* d_out, int out_size, void* d_ws, size_t ws_size,
                              hipStream_t stream) {
    const float* z   = (const float*)d_in[0];   // [16, 256, 2048]
    const float* emb = (const float*)d_in[1];   // [8192, 256]
    float* out = (float*)d_out;

    char* ws = (char*)d_ws;
    const size_t oZH = 0;
    const size_t oZL = oZH + 16777216;
    const size_t oEH = oZL + 16777216;
    const size_t oEL = oEH + 4194304;
    const size_t oCD = oEL + 4194304;          // cand: 8*32768*2*8 = 4 MB
    const size_t oA3 = oCD + 4194304;
    const size_t oKY = oA3 + 131072;
    const size_t oLS = oKY + 131072;
    const size_t oCN = oLS + 131072;
    const size_t needed = oCN + 64;

    if (ws_size >= needed) {
        unsigned short* zh = (unsigned short*)(ws + oZH);
        unsigned short* zl = (unsigned short*)(ws + oZL);
        unsigned short* eh = (unsigned short*)(ws + oEH);
        unsigned short* el = (unsigned short*)(ws + oEL);
        u64*   cand = (u64*)(ws + oCD);
        float* A32  = (float*)(ws + oA3);
        int*   keys = (int*)(ws + oKY);
        int*   list = (int*)(ws + oLS);
        int*   cnt  = (int*)(ws + oCN);

        k_prepA <<<512,  256, 0, stream>>>(z, A32, cnt, out);
        k_convZ <<<2048, 256, 0, stream>>>(z, zh, zl);
        k_convE <<<1024, 256, 0, stream>>>(emb, eh, el);
        k_gemm  <<<2048, 256, 0, stream>>>(zh, zl, eh, el, cand);
        k_select<<<128,  256, 0, stream>>>(cand, A32, keys, cnt, list);
        k_refine<<<512,  256, 0, stream>>>(z, emb, A32, list, cnt, keys);
        k_out   <<<128,  256, 0, stream>>>(z, emb, keys, out);
    } else {
        // fallback: round-3 proven path (~1.5 MB ws)
        u64*   cand2 = (u64*)ws;                          // 1 MB
        float* A32   = (float*)(ws + 1048576);            // 128 KB
        int*   keys  = (int*)(ws + 1048576 + 131072);
        int*   list  = (int*)(ws + 1048576 + 262144);
        int*   cnt   = (int*)(ws + 1048576 + 393216);

        k_prepA    <<<512,          256, 0, stream>>>(z, A32, cnt, out);
        k_argmin_fb<<<dim3(256, 2), 256, 0, stream>>>(z, emb, cand2);
        k_select_fb<<<128,          256, 0, stream>>>(cand2, A32, keys, cnt, list);
        k_refine   <<<512,          256, 0, stream>>>(z, emb, A32, list, cnt, keys);
        k_out      <<<128,          256, 0, stream>>>(z, emb, keys, out);
    }
}

// Round 4
// 1447.848 us; speedup vs baseline: 1.2848x; 1.2848x over previous
//
#include <hip/hip_runtime.h>
#include <cstdint>

#define BB 16
#define DD 256
#define TT 2048
#define KK 8192
#define NN 32768            // BB*TT
#define QQ 8388608          // BB*DD*TT
typedef unsigned long long u64;

typedef __attribute__((ext_vector_type(8))) short short8;   // 8 bf16 (4 VGPRs)
typedef __attribute__((ext_vector_type(4))) float f32x4;    // MFMA C/D

#define GLOBAL_AS __attribute__((address_space(1)))
#define LDS_AS    __attribute__((address_space(3)))

// async global->LDS, 16 B per lane; LDS dest = wave-uniform base + lane*16
__device__ __forceinline__ void async_copy16(void* l, const void* g) {
    __builtin_amdgcn_global_load_lds((const GLOBAL_AS unsigned int*)g,
                                     (LDS_AS unsigned int*)l, 16, 0, 0);
}

__device__ __forceinline__ unsigned mapf(float f) {
    unsigned u = __float_as_uint(f);
    return (u & 0x80000000u) ? ~u : (u | 0x80000000u);
}
__device__ __forceinline__ float unmapf(unsigned u) {
    return __uint_as_float((u & 0x80000000u) ? (u & 0x7FFFFFFFu) : ~u);
}
__device__ __forceinline__ unsigned bf16_rne(float v) {
    unsigned ui = __float_as_uint(v);
    return (ui + 0x7FFFu + ((ui >> 16) & 1)) >> 16;
}

// ---------------------------------------------------------------------------
// A32[n] = fp32(fp64 sum of z_n^2); zero cnt & loss. grid 512 x 256
// ---------------------------------------------------------------------------
__global__ __launch_bounds__(256) void k_prepA(const float* __restrict__ z,
                                               float* __restrict__ A32,
                                               int* __restrict__ cnt,
                                               float* __restrict__ out) {
    __shared__ double sd[256];
    int tid = threadIdx.x;
    int r = tid & 63;               // row within block (coalesced over t)
    int c = tid >> 6;               // wave -> d quarter
    int n = blockIdx.x * 64 + r;
    if (blockIdx.x == 0 && tid == 0) { *cnt = 0; out[QQ] = 0.0f; }
    int b = n >> 11, t = n & 2047;
    const float* zp = z + (size_t)b * 524288 + t;
    double s = 0.0;
#pragma unroll 8
    for (int i = 0; i < 64; i++) {
        float v = zp[(size_t)(c * 64 + i) * 2048];
        s = fma((double)v, (double)v, s);
    }
    sd[tid] = s;
    __syncthreads();
    if (c == 0) {
        double tot = sd[r] + sd[64 + r] + sd[128 + r] + sd[192 + r];
        A32[n] = (float)tot;
    }
}

// ---------------------------------------------------------------------------
// z [b][d][t] fp32 -> zh/zl [n][d] bf16 hi/lo, 16B stores. grid 2048 x 256
// ---------------------------------------------------------------------------
__global__ __launch_bounds__(256) void k_convZ(const float* __restrict__ z,
                                               unsigned short* __restrict__ zh,
                                               unsigned short* __restrict__ zl) {
    __shared__ float sm[64][65];
    int tid = threadIdx.x;
    int bid = blockIdx.x;
    int b  = bid >> 7;
    int dt = (bid >> 5) & 3;
    int tt = bid & 31;
    const float* zp = z + (size_t)b * 524288 + (size_t)dt * 131072 + tt * 64;
#pragma unroll
    for (int i = 0; i < 16; i++) {
        int idx = tid + 256 * i;
        int d = idx >> 6, t = idx & 63;
        sm[d][t] = zp[(size_t)d * 2048 + t];
    }
    __syncthreads();
    int d0 = (tid & 7) * 8;
#pragma unroll
    for (int i = 0; i < 2; i++) {
        int t = (tid >> 3) + 32 * i;
        size_t o = ((size_t)(b * 2048 + tt * 64 + t)) * 256 + dt * 64 + d0;
        short8 hv, lv;
#pragma unroll
        for (int j = 0; j < 8; j++) {
            float v = sm[d0 + j][t];
            unsigned hb = bf16_rne(v);
            float hf = __uint_as_float(hb << 16);
            unsigned lb = bf16_rne(v - hf);
            hv[j] = (short)hb;
            lv[j] = (short)lb;
        }
        *(short8*)(zh + o) = hv;
        *(short8*)(zl + o) = lv;
    }
}

// ---------------------------------------------------------------------------
// emb [k][d] fp32 -> eh/el bf16 hi/lo. grid 1024 x 256
// ---------------------------------------------------------------------------
__global__ __launch_bounds__(256) void k_convE(const float* __restrict__ emb,
                                               unsigned short* __restrict__ eh,
                                               unsigned short* __restrict__ el) {
    int base = (blockIdx.x * 256 + threadIdx.x) * 8;
    float4 v0 = *(const float4*)(emb + base);
    float4 v1 = *(const float4*)(emb + base + 4);
    float vv[8] = {v0.x, v0.y, v0.z, v0.w, v1.x, v1.y, v1.z, v1.w};
    short8 hv, lv;
#pragma unroll
    for (int i = 0; i < 8; i++) {
        unsigned hb = bf16_rne(vv[i]);
        float hf = __uint_as_float(hb << 16);
        unsigned lb = bf16_rne(vv[i] - hf);
        hv[i] = (short)hb;
        lv[i] = (short)lb;
    }
    *(short8*)(eh + base) = hv;
    *(short8*)(el + base) = lv;
}

// ---------------------------------------------------------------------------
// MFMA distance GEMM v6 (hybrid): score = -2*(zh.eh + zh.el + zl.eh)
// B (codes, shared by both wr-half waves) double-buffered in LDS via
// global_load_lds; A (rows, wave-private) loaded DIRECT from global in MFMA
// fragment layout (v5-proven addressing, L2-resident 128KB/mt). Halves LDS
// traffic (16 -> 8 ds_read_b128/wave/it) and LDS footprint (64 -> 32 KB) ->
// 3 blocks/CU (12 waves, 3/SIMD). One __syncthreads per K-step. Per-acc MFMA
// chain order identical to v4 -> bit-identical scores.
// Block: 128 rows x 1024 codes (8 slabs of 128). grid 2048 (mt=bid&255, ng=bid>>8).
// ---------------------------------------------------------------------------
__global__ __launch_bounds__(256, 3) void k_gemm(const unsigned short* __restrict__ zh,
                                                 const unsigned short* __restrict__ zl,
                                                 const unsigned short* __restrict__ eh,
                                                 const unsigned short* __restrict__ el,
                                                 u64* __restrict__ cand) {
    // fragment-major: tile t (16 codes x 32 k) occupies [t*512, t*512+512) shorts;
    // slot l (16B) within a tile holds (row = l&15, k-chunk = l>>4)
    // pool[buf][arr][...]: arr 0=Beh 1=Bel; 32 KB total.
    // rtop (4 KB) aliases pool[0][0] -- only used after the final barrier.
    __shared__ __align__(16) unsigned short pool[2][2][4096];

    int tid  = threadIdx.x;
    int w    = tid >> 6;
    int lane = tid & 63;
    int lm   = lane & 15;
    int q    = lane >> 4;
    int wr   = w >> 1;              // row half   (0/1): rows wr*64..wr*64+63
    int wc   = w & 1;               // code half  (0/1): codes wc*64..wc*64+63
    int wc4  = wc * 4;              // first B tile for this wave

    int bid = blockIdx.x;
    int mt  = bid & 255;
    int ng  = bid >> 8;

    // staging: lane fetches global (row = lane&15 within tile, chunk = lane>>4)
    int srow   = lane & 15;
    int schunk = lane >> 4;
    int t0 = 2 * w, t1 = 2 * w + 1;               // this wave's staged B tiles
    size_t ga0 = (size_t)(t0 * 16 + srow) * 256;  // + koff later
    size_t ga1 = (size_t)(t1 * 16 + srow) * 256;

    // A direct-load bases (per-lane fragment addressing, v5-proven):
    // global row = mt*128 + wr*64 + mi*16 + lm ; chunk q*8 + kc*32
    const unsigned short* Ahw = zh + (size_t)(mt * 128 + wr * 64 + lm) * 256 + q * 8;
    const unsigned short* Alw = zl + (size_t)(mt * 128 + wr * 64 + lm) * 256 + q * 8;

    auto stage = [&](int nb, int it2) {
        int ns2  = it2 >> 3;
        int kc2  = it2 & 7;
        int koff = kc2 * 32 + schunk * 8;
        size_t boff = (size_t)(ng * 1024 + ns2 * 128) * 256;
        const unsigned short* Bgh = eh + boff;
        const unsigned short* Bgl = el + boff;
        async_copy16(&pool[nb][0][t0 * 512], Bgh + ga0 + koff);
        async_copy16(&pool[nb][0][t1 * 512], Bgh + ga1 + koff);
        async_copy16(&pool[nb][1][t0 * 512], Bgl + ga0 + koff);
        async_copy16(&pool[nb][1][t1 * 512], Bgl + ga1 + koff);
    };

    // float-domain top-2 per (mi,reg): track MAX of acc (score = -2*acc).
    float v1a[4][4], v2a[4][4];
    int   i1a[4][4], i2a[4][4];
#pragma unroll
    for (int mi = 0; mi < 4; mi++)
#pragma unroll
        for (int reg = 0; reg < 4; reg++) {
            v1a[mi][reg] = -3.4e38f; v2a[mi][reg] = -3.4e38f;
            i1a[mi][reg] = 0;        i2a[mi][reg] = 0;
        }

    f32x4 acc[4][4];

    // prologue: fill buffer 0 with iteration 0
    stage(0, 0);
    __syncthreads();

    for (int it = 0; it < 64; ++it) {
        int cur = it & 1;
        if (it + 1 < 64) stage(cur ^ 1, it + 1);   // prefetch next K-step

        if ((it & 7) == 0) {
#pragma unroll
            for (int mi = 0; mi < 4; mi++)
#pragma unroll
                for (int ni = 0; ni < 4; ni++) acc[mi][ni] = (f32x4){0.f, 0.f, 0.f, 0.f};
        }

        int koff = (it & 7) * 32;

        // A fragments direct from global (L2-resident, wave-private)
        short8 fah[4], fal[4];
#pragma unroll
        for (int mi = 0; mi < 4; mi++) {
            fah[mi] = *(const short8*)(Ahw + mi * 4096 + koff);
            fal[mi] = *(const short8*)(Alw + mi * 4096 + koff);
        }

        const unsigned short* pBh = pool[cur][0];
        const unsigned short* pBl = pool[cur][1];

        __builtin_amdgcn_s_setprio(1);
#pragma unroll
        for (int ni = 0; ni < 4; ni++) {
            short8 fbh = *(const short8*)&pBh[(wc4 + ni) * 512 + lane * 8];
            short8 fbl = *(const short8*)&pBl[(wc4 + ni) * 512 + lane * 8];
#pragma unroll
            for (int mi = 0; mi < 4; mi++) {
                acc[mi][ni] = __builtin_amdgcn_mfma_f32_16x16x32_bf16(fah[mi], fbh, acc[mi][ni], 0, 0, 0);
                acc[mi][ni] = __builtin_amdgcn_mfma_f32_16x16x32_bf16(fal[mi], fbh, acc[mi][ni], 0, 0, 0);
                acc[mi][ni] = __builtin_amdgcn_mfma_f32_16x16x32_bf16(fah[mi], fbl, acc[mi][ni], 0, 0, 0);
            }
        }
        __builtin_amdgcn_s_setprio(0);

        if ((it & 7) == 7) {   // slab complete: fold into per-lane top-2
            int idb = ng * 1024 + (it >> 3) * 128 + wc * 64 + lm;
#pragma unroll
            for (int ni = 0; ni < 4; ni++) {
                int id = idb + ni * 16;
#pragma unroll
                for (int mi = 0; mi < 4; mi++)
#pragma unroll
                    for (int reg = 0; reg < 4; reg++) {
                        float v = acc[mi][ni][reg];
                        bool c2 = v > v2a[mi][reg];
                        bool c1 = v > v1a[mi][reg];
                        v2a[mi][reg] = c2 ? v  : v2a[mi][reg];
                        i2a[mi][reg] = c2 ? id : i2a[mi][reg];
                        v2a[mi][reg] = c1 ? v1a[mi][reg] : v2a[mi][reg];
                        i2a[mi][reg] = c1 ? i1a[mi][reg] : i2a[mi][reg];
                        v1a[mi][reg] = c1 ? v  : v1a[mi][reg];
                        i1a[mi][reg] = c1 ? id : i1a[mi][reg];
                    }
            }
        }
        // drains prefetch (cur^1 ready) + all waves done reading cur
        __syncthreads();
    }

    // pack to mapf-u64, butterfly across the 16 lm-lanes (bits 0..3 of lane)
    u64* rtop = (u64*)&pool[0][0][0];   // aliased; all buffer reads are done
#pragma unroll
    for (int mi = 0; mi < 4; mi++)
#pragma unroll
        for (int reg = 0; reg < 4; reg++) {
            float s1 = -2.0f * v1a[mi][reg];
            float s2 = -2.0f * v2a[mi][reg];
            u64 p1 = ((u64)mapf(s1) << 32) | (unsigned)i1a[mi][reg];
            u64 p2 = ((u64)mapf(s2) << 32) | (unsigned)i2a[mi][reg];
#pragma unroll
            for (int msk = 1; msk <= 8; msk <<= 1) {
                u64 q1 = __shfl_xor(p1, msk, 64);
                u64 q2 = __shfl_xor(p2, msk, 64);
                u64 n1 = (p1 < q1) ? p1 : q1;
                u64 hi = (p1 < q1) ? q1 : p1;
                u64 n2 = (q2 < p2) ? q2 : p2;
                n2 = (hi < n2) ? hi : n2;
                p1 = n1; p2 = n2;
            }
            if (lm == 0) {
                int m = wc * 128 + wr * 64 + mi * 16 + q * 4 + reg;
                rtop[m * 2]     = p1;
                rtop[m * 2 + 1] = p2;
            }
        }
    __syncthreads();
    if (tid < 128) {   // merge the two code-halves for each row
        u64 a1 = rtop[tid * 2],         a2 = rtop[tid * 2 + 1];
        u64 b1 = rtop[(128 + tid) * 2], b2 = rtop[(128 + tid) * 2 + 1];
        u64 m1 = (a1 < b1) ? a1 : b1;
        u64 lo = (a1 < b1) ? b1 : a1;
        u64 m2 = (a2 < b2) ? a2 : b2;
        m2 = (lo < m2) ? lo : m2;
        size_t o = ((size_t)ng * 32768 + (size_t)mt * 128 + tid) * 2;
        cand[o]     = m1;
        cand[o + 1] = m2;
    }
}

// ---------------------------------------------------------------------------
// select (MFMA path): merge 8 (top1,top2) pairs; commit or flag. grid 128
// ---------------------------------------------------------------------------
__global__ __launch_bounds__(256) void k_select(const u64* __restrict__ cand,
                                                const float* __restrict__ A32,
                                                int* __restrict__ keys,
                                                int* __restrict__ cnt,
                                                int* __restrict__ list) {
    int n = blockIdx.x * 256 + threadIdx.x;
    u64 m1 = cand[(size_t)n * 2];
    u64 m2 = cand[(size_t)n * 2 + 1];
#pragma unroll
    for (int j = 1; j < 8; j++) {
        u64 c1 = cand[((size_t)j * 32768 + n) * 2];
        u64 c2 = cand[((size_t)j * 32768 + n) * 2 + 1];
        if (c1 < m1) { m2 = (m1 < m2) ? m1 : m2; m1 = c1; }
        else         { m2 = (c1 < m2) ? c1 : m2; }
        m2 = (c2 < m2) ? c2 : m2;
    }
    keys[n] = (int)(unsigned)(m1 & 0xFFFFFFFFull);
    float f1 = unmapf((unsigned)(m1 >> 32));
    float f2 = unmapf((unsigned)(m2 >> 32));
    float W = ((A32[n] >= 255.9f) ? 3.4e-5f : 1.8e-5f) + 4e-6f;  // + 2*eps(bf16x3)
    if (f2 - f1 <= W) {
        int p = atomicAdd(cnt, 1);
        list[p] = n;
    }
}

// ---------------------------------------------------------------------------
// FALLBACK path (round-3 proven): fp32 VALU GEMM argmin + its select
// ---------------------------------------------------------------------------
__global__ __launch_bounds__(256) void k_argmin_fb(const float* __restrict__ z,
                                                   const float* __restrict__ emb,
                                                   u64* __restrict__ cand2) {
    __shared__ __align__(16) float smem[8192];
    float* As = smem;
    float* Bs = smem + 4096;

    int tid = threadIdx.x;
    int tx  = tid & 15;
    int ty  = tid >> 4;
    int mt  = blockIdx.x;
    int kh  = blockIdx.y;

    int bimg = mt >> 4;
    int t0   = (mt & 15) << 7;
    const float* zb = z + (size_t)bimg * (DD * TT) + t0;

    float bestv[8], bestv2[8];
    int   besti[8];
#pragma unroll
    for (int i = 0; i < 8; i++) { bestv[i] = 3.4e38f; bestv2[i] = 3.4e38f; besti[i] = 0; }

    int qa = tid & 31, ra = tid >> 5;
    int jb = tid >> 3, db = tid & 7;
    int swz_t = (tx & 7) << 2;

    for (int kc = 0; kc < 32; kc++) {
        int k0 = kh * 4096 + kc * 128;
        float acc[8][8];
#pragma unroll
        for (int i = 0; i < 8; i++)
#pragma unroll
            for (int j = 0; j < 8; j++) acc[i][j] = 0.0f;

        for (int dc = 0; dc < 8; dc++) {
            int d0 = dc * 32;
            __syncthreads();
#pragma unroll
            for (int s = 0; s < 4; s++) {
                int d = ra + 8 * s;
                float4 v = *(const float4*)(zb + (size_t)(d0 + d) * TT + 4 * qa);
                *(float4*)(As + d * 128 + 4 * qa) = v;
            }
#pragma unroll
            for (int s = 0; s < 4; s++) {
                int row = jb + 32 * s;
                float4 v = *(const float4*)(emb + (size_t)(k0 + row) * DD + d0 + 4 * db);
                int col  = (4 * db) ^ ((row & 7) << 2);
                *(float4*)(Bs + row * 32 + col) = v;
            }
            __syncthreads();
#pragma unroll
            for (int g = 0; g < 8; g++) {
                float4 bf[8];
#pragma unroll
                for (int in = 0; in < 8; in++) {
                    int nn = in * 16 + tx;
                    bf[in] = *(const float4*)(Bs + nn * 32 + ((4 * g) ^ swz_t));
                }
#pragma unroll
                for (int j = 0; j < 4; j++) {
                    int d = 4 * g + j;
                    float4 a0 = *(const float4*)(As + d * 128 + ty * 8);
                    float4 a1 = *(const float4*)(As + d * 128 + ty * 8 + 4);
                    float av[8] = {a0.x, a0.y, a0.z, a0.w, a1.x, a1.y, a1.z, a1.w};
#pragma unroll
                    for (int im = 0; im < 8; im++) {
#pragma unroll
                        for (int in = 0; in < 8; in++) {
                            const float* bfp = (const float*)&bf[in];
                            acc[im][in] = fmaf(av[im], bfp[j], acc[im][in]);
                        }
                    }
                }
            }
        }
#pragma unroll
        for (int in = 0; in < 8; in++) {
            int k = k0 + in * 16 + tx;
#pragma unroll
            for (int im = 0; im < 8; im++) {
                float s = -2.0f * acc[im][in];
                if (s < bestv[im]) { bestv2[im] = bestv[im]; bestv[im] = s; besti[im] = k; }
                else if (s < bestv2[im]) { bestv2[im] = s; }
            }
        }
    }

    __syncthreads();
    u64* red = (u64*)smem;
#pragma unroll
    for (int im = 0; im < 8; im++) {
        int r = ty * 8 + im;
        red[r * 32 + tx * 2 + 0] = ((u64)mapf(bestv[im]) << 32) | (unsigned)besti[im];
        red[r * 32 + tx * 2 + 1] = ((u64)mapf(bestv2[im]) << 32);
    }
    __syncthreads();
    if (tid < 128) {
        const u64* base = red + tid * 32;
        u64 p1 = base[0];
        u64 s2 = base[1];
#pragma unroll
        for (int t = 1; t < 16; t++) {
            u64 c1 = base[t * 2], c2 = base[t * 2 + 1];
            if (c1 < p1) { s2 = (p1 < s2) ? p1 : s2; p1 = c1; }
            else         { s2 = (c1 < s2) ? c1 : s2; }
            s2 = (c2 < s2) ? c2 : s2;
        }
        int n = mt * 128 + tid;
        cand2[(size_t)n * 4 + kh * 2]     = p1;
        cand2[(size_t)n * 4 + kh * 2 + 1] = s2;
    }
}

__global__ __launch_bounds__(256) void k_select_fb(const u64* __restrict__ cand2,
                                                   const float* __restrict__ A32,
                                                   int* __restrict__ keys,
                                                   int* __restrict__ cnt,
                                                   int* __restrict__ list) {
    int n = blockIdx.x * 256 + threadIdx.x;
    u64 a1 = cand2[(size_t)n * 4 + 0], a2 = cand2[(size_t)n * 4 + 1];
    u64 b1 = cand2[(size_t)n * 4 + 2], b2 = cand2[(size_t)n * 4 + 3];
    u64 m1 = (a1 < b1) ? a1 : b1;
    u64 lo = (a1 < b1) ? b1 : a1;
    u64 m2 = (a2 < b2) ? a2 : b2;
    m2 = (lo < m2) ? lo : m2;

    keys[n] = (int)(unsigned)(m1 & 0xFFFFFFFFull);
    float f1 = unmapf((unsigned)(m1 >> 32));
    float f2 = unmapf((unsigned)(m2 >> 32));
    float W = (A32[n] >= 255.9f) ? 3.4e-5f : 1.8e-5f;
    if (f2 - f1 <= W) {
        int p = atomicAdd(cnt, 1);
        list[p] = n;
    }
}

// ---------------------------------------------------------------------------
// exact np-fp32 emulation for flagged rows (round-3 proven). grid 512
// ---------------------------------------------------------------------------
__global__ __launch_bounds__(256) void k_refine(const float* __restrict__ z,
                                                const float* __restrict__ emb,
                                                const float* __restrict__ A32,
                                                const int* __restrict__ list,
                                                const int* __restrict__ cnt,
                                                int* __restrict__ keys) {
    __shared__ __align__(16) float zs[256][8];
    __shared__ float aA[8];
    __shared__ int   ln[8];
    __shared__ u64   wred[4 * 8];

    int tid = threadIdx.x, lane = tid & 63, w = tid >> 6;
    int count = *cnt;
    int ngroups = (count + 7) >> 3;

    for (int g = blockIdx.x; g < ngroups; g += gridDim.x) {
        __syncthreads();
#pragma unroll
        for (int r = 0; r < 8; r++) {
            int row = g * 8 + r;
            int n   = list[(row < count) ? row : 0];
            int b = n >> 11, t = n & 2047;
            zs[tid][r] = z[(size_t)b * (DD * TT) + (size_t)tid * TT + t];
            if (tid == 0) { ln[r] = (row < count) ? n : -1; aA[r] = A32[n]; }
        }
        __syncthreads();

        u64 best[8];
#pragma unroll
        for (int r = 0; r < 8; r++) best[r] = 0xFFFFFFFFFFFFFFFFull;

        float Ar[8];
#pragma unroll
        for (int r = 0; r < 8; r++) Ar[r] = aA[r];

        for (int c = 0; c < 8; c++) {
            int kbase = c * 1024 + tid;
            const float4* e0 = (const float4*)(emb + (size_t)(kbase)       * DD);
            const float4* e1 = (const float4*)(emb + (size_t)(kbase + 256) * DD);
            const float4* e2 = (const float4*)(emb + (size_t)(kbase + 512) * DD);
            const float4* e3 = (const float4*)(emb + (size_t)(kbase + 768) * DD);
            float acc[4][8];
#pragma unroll
            for (int qq = 0; qq < 4; qq++)
#pragma unroll
                for (int r = 0; r < 8; r++) acc[qq][r] = 0.0f;

            for (int d4 = 0; d4 < 64; d4++) {
                float4 v0 = e0[d4], v1 = e1[d4], v2 = e2[d4], v3 = e3[d4];
                const float* p0 = (const float*)&v0;
                const float* p1 = (const float*)&v1;
                const float* p2 = (const float*)&v2;
                const float* p3 = (const float*)&v3;
#pragma unroll
                for (int i = 0; i < 4; i++) {
                    int d = 4 * d4 + i;
                    float4 za = *(const float4*)&zs[d][0];
                    float4 zb2 = *(const float4*)&zs[d][4];
                    const float* zr  = (const float*)&za;
                    const float* zr2 = (const float*)&zb2;
#pragma unroll
                    for (int r = 0; r < 4; r++) {
                        acc[0][r]     = fmaf(zr[r],  p0[i], acc[0][r]);
                        acc[1][r]     = fmaf(zr[r],  p1[i], acc[1][r]);
                        acc[2][r]     = fmaf(zr[r],  p2[i], acc[2][r]);
                        acc[3][r]     = fmaf(zr[r],  p3[i], acc[3][r]);
                        acc[0][r + 4] = fmaf(zr2[r], p0[i], acc[0][r + 4]);
                        acc[1][r + 4] = fmaf(zr2[r], p1[i], acc[1][r + 4]);
                        acc[2][r + 4] = fmaf(zr2[r], p2[i], acc[2][r + 4]);
                        acc[3][r + 4] = fmaf(zr2[r], p3[i], acc[3][r + 4]);
                    }
                }
            }
#pragma unroll
            for (int qq = 0; qq < 4; qq++) {
                int k = kbase + qq * 256;
#pragma unroll
                for (int r = 0; r < 8; r++) {
                    float dk = Ar[r] - 2.0f * acc[qq][r];
                    u64 p = ((u64)mapf(dk) << 32) | (unsigned)k;
                    best[r] = (p < best[r]) ? p : best[r];
                }
            }
        }
#pragma unroll
        for (int r = 0; r < 8; r++) {
            u64 v = best[r];
            for (int off = 32; off; off >>= 1) {
                u64 o = __shfl_down(v, off, 64);
                v = (o < v) ? o : v;
            }
            if (lane == 0) wred[w * 8 + r] = v;
        }
        __syncthreads();
        if (tid < 8) {
            u64 v = wred[tid];
#pragma unroll
            for (int j = 1; j < 4; j++) {
                u64 o = wred[j * 8 + tid];
                v = (o < v) ? o : v;
            }
            int n = ln[tid];
            if (n >= 0) keys[n] = (int)(unsigned)(v & 0xFFFFFFFFull);
        }
        __syncthreads();
    }
}

// ---------------------------------------------------------------------------
// gather quantized, write outputs, loss = 1.25 * mean((q - z)^2)
// ---------------------------------------------------------------------------
__global__ __launch_bounds__(256) void k_out(const float* __restrict__ z,
                                             const float* __restrict__ emb,
                                             const int* __restrict__ keys,
                                             float* __restrict__ out) {
    int tid = threadIdx.x;
    int n   = blockIdx.x * 256 + tid;
    int b   = n >> 11;
    int t   = n & 2047;
    int idx = keys[n];
    out[QQ + 1 + n] = (float)idx;

    const float4* erow = (const float4*)(emb + (size_t)idx * DD);
    const float*  zp   = z   + (size_t)b * (DD * TT) + t;
    float*        op   = out + (size_t)b * (DD * TT) + t;

    float ssd = 0.0f;
#pragma unroll 4
    for (int d4 = 0; d4 < 64; d4++) {
        float4 qv = erow[d4];
        float qa[4] = {qv.x, qv.y, qv.z, qv.w};
#pragma unroll
        for (int r = 0; r < 4; r++) {
            int d = 4 * d4 + r;
            float zv = zp[(size_t)d * TT];
            float df = qa[r] - zv;
            ssd = fmaf(df, df, ssd);
            op[(size_t)d * TT] = qa[r];
        }
    }
    for (int off = 32; off; off >>= 1) ssd += __shfl_down(ssd, off, 64);
    __shared__ float red[4];
    if ((tid & 63) == 0) red[tid >> 6] = ssd;
    __syncthreads();
    if (tid == 0) {
        float tot = red[0] + red[1] + red[2] + red[3];
        atomicAdd(out + QQ, tot * (1.25f / (float)QQ));
    }
}

// ---------------------------------------------------------------------------
extern "C" void kernel_launch(void* const* d_in, const int* in_sizes, int n_in,
                              void* d_out, int out_size, void* d_ws, size_t ws_size,
                              hipStream_t stream) {
    const float* z   = (const float*)d_in[0];   // [16, 256, 2048]
    const float* emb = (const float*)d_in[1];   // [8192, 256]
    float* out = (float*)d_out;

    char* ws = (char*)d_ws;
    const size_t oZH = 0;
    const size_t oZL = oZH + 16777216;
    const size_t oEH = oZL + 16777216;
    const size_t oEL = oEH + 4194304;
    const size_t oCD = oEL + 4194304;          // cand: 8*32768*2*8 = 4 MB
    const size_t oA3 = oCD + 4194304;
    const size_t oKY = oA3 + 131072;
    const size_t oLS = oKY + 131072;
    const size_t oCN = oLS + 131072;
    const size_t needed = oCN + 64;

    if (ws_size >= needed) {
        unsigned short* zh = (unsigned short*)(ws + oZH);
        unsigned short* zl = (unsigned short*)(ws + oZL);
        unsigned short* eh = (unsigned short*)(ws + oEH);
        unsigned short* el = (unsigned short*)(ws + oEL);
        u64*   cand = (u64*)(ws + oCD);
        float* A32  = (float*)(ws + oA3);
        int*   keys = (int*)(ws + oKY);
        int*   list = (int*)(ws + oLS);
        int*   cnt  = (int*)(ws + oCN);

        k_prepA <<<512,  256, 0, stream>>>(z, A32, cnt, out);
        k_convZ <<<2048, 256, 0, stream>>>(z, zh, zl);
        k_convE <<<1024, 256, 0, stream>>>(emb, eh, el);
        k_gemm  <<<2048, 256, 0, stream>>>(zh, zl, eh, el, cand);
        k_select<<<128,  256, 0, stream>>>(cand, A32, keys, cnt, list);
        k_refine<<<512,  256, 0, stream>>>(z, emb, A32, list, cnt, keys);
        k_out   <<<128,  256, 0, stream>>>(z, emb, keys, out);
    } else {
        // fallback: round-3 proven path (~1.5 MB ws)
        u64*   cand2 = (u64*)ws;                          // 1 MB
        float* A32   = (float*)(ws + 1048576);            // 128 KB
        int*   keys  = (int*)(ws + 1048576 + 131072);
        int*   list  = (int*)(ws + 1048576 + 262144);
        int*   cnt   = (int*)(ws + 1048576 + 393216);

        k_prepA    <<<512,          256, 0, stream>>>(z, A32, cnt, out);
        k_argmin_fb<<<dim3(256, 2), 256, 0, stream>>>(z, emb, cand2);
        k_select_fb<<<128,          256, 0, stream>>>(cand2, A32, keys, cnt, list);
        k_refine   <<<512,          256, 0, stream>>>(z, emb, A32, list, cnt, keys);
        k_out      <<<128,          256, 0, stream>>>(z, emb, keys, out);
    }
}

// Round 5
// 1364.463 us; speedup vs baseline: 1.3633x; 1.0611x over previous
//
#include <hip/hip_runtime.h>
#include <cstdint>

#define BB 16
#define DD 256
#define TT 2048
#define KK 8192
#define NN 32768            // BB*TT
#define QQ 8388608          // BB*DD*TT
typedef unsigned long long u64;

typedef __attribute__((ext_vector_type(8))) short short8;   // 8 bf16 (4 VGPRs)
typedef __attribute__((ext_vector_type(4))) float f32x4;    // MFMA C/D

#define GLOBAL_AS __attribute__((address_space(1)))
#define LDS_AS    __attribute__((address_space(3)))

// async global->LDS, 16 B per lane; LDS dest = wave-uniform base + lane*16
__device__ __forceinline__ void async_copy16(void* l, const void* g) {
    __builtin_amdgcn_global_load_lds((const GLOBAL_AS unsigned int*)g,
                                     (LDS_AS unsigned int*)l, 16, 0, 0);
}

__device__ __forceinline__ unsigned mapf(float f) {
    unsigned u = __float_as_uint(f);
    return (u & 0x80000000u) ? ~u : (u | 0x80000000u);
}
__device__ __forceinline__ float unmapf(unsigned u) {
    return __uint_as_float((u & 0x80000000u) ? (u & 0x7FFFFFFFu) : ~u);
}
__device__ __forceinline__ unsigned bf16_rne(float v) {
    unsigned ui = __float_as_uint(v);
    return (ui + 0x7FFFu + ((ui >> 16) & 1)) >> 16;
}

// ---------------------------------------------------------------------------
// A32[n] = fp32(fp64 sum of z_n^2); zero cnt & loss. grid 512 x 256
// ---------------------------------------------------------------------------
__global__ __launch_bounds__(256) void k_prepA(const float* __restrict__ z,
                                               float* __restrict__ A32,
                                               int* __restrict__ cnt,
                                               float* __restrict__ out) {
    __shared__ double sd[256];
    int tid = threadIdx.x;
    int r = tid & 63;               // row within block (coalesced over t)
    int c = tid >> 6;               // wave -> d quarter
    int n = blockIdx.x * 64 + r;
    if (blockIdx.x == 0 && tid == 0) { *cnt = 0; out[QQ] = 0.0f; }
    int b = n >> 11, t = n & 2047;
    const float* zp = z + (size_t)b * 524288 + t;
    double s = 0.0;
#pragma unroll 8
    for (int i = 0; i < 64; i++) {
        float v = zp[(size_t)(c * 64 + i) * 2048];
        s = fma((double)v, (double)v, s);
    }
    sd[tid] = s;
    __syncthreads();
    if (c == 0) {
        double tot = sd[r] + sd[64 + r] + sd[128 + r] + sd[192 + r];
        A32[n] = (float)tot;
    }
}

// ---------------------------------------------------------------------------
// z [b][d][t] fp32 -> zh/zl [n][d] bf16 hi/lo, 16B stores. grid 2048 x 256
// ---------------------------------------------------------------------------
__global__ __launch_bounds__(256) void k_convZ(const float* __restrict__ z,
                                               unsigned short* __restrict__ zh,
                                               unsigned short* __restrict__ zl) {
    __shared__ float sm[64][65];
    int tid = threadIdx.x;
    int bid = blockIdx.x;
    int b  = bid >> 7;
    int dt = (bid >> 5) & 3;
    int tt = bid & 31;
    const float* zp = z + (size_t)b * 524288 + (size_t)dt * 131072 + tt * 64;
#pragma unroll
    for (int i = 0; i < 16; i++) {
        int idx = tid + 256 * i;
        int d = idx >> 6, t = idx & 63;
        sm[d][t] = zp[(size_t)d * 2048 + t];
    }
    __syncthreads();
    int d0 = (tid & 7) * 8;
#pragma unroll
    for (int i = 0; i < 2; i++) {
        int t = (tid >> 3) + 32 * i;
        size_t o = ((size_t)(b * 2048 + tt * 64 + t)) * 256 + dt * 64 + d0;
        short8 hv, lv;
#pragma unroll
        for (int j = 0; j < 8; j++) {
            float v = sm[d0 + j][t];
            unsigned hb = bf16_rne(v);
            float hf = __uint_as_float(hb << 16);
            unsigned lb = bf16_rne(v - hf);
            hv[j] = (short)hb;
            lv[j] = (short)lb;
        }
        *(short8*)(zh + o) = hv;
        *(short8*)(zl + o) = lv;
    }
}

// ---------------------------------------------------------------------------
// emb [k][d] fp32 -> eh/el bf16 hi/lo. grid 1024 x 256
// ---------------------------------------------------------------------------
__global__ __launch_bounds__(256) void k_convE(const float* __restrict__ emb,
                                               unsigned short* __restrict__ eh,
                                               unsigned short* __restrict__ el) {
    int base = (blockIdx.x * 256 + threadIdx.x) * 8;
    float4 v0 = *(const float4*)(emb + base);
    float4 v1 = *(const float4*)(emb + base + 4);
    float vv[8] = {v0.x, v0.y, v0.z, v0.w, v1.x, v1.y, v1.z, v1.w};
    short8 hv, lv;
#pragma unroll
    for (int i = 0; i < 8; i++) {
        unsigned hb = bf16_rne(vv[i]);
        float hf = __uint_as_float(hb << 16);
        unsigned lb = bf16_rne(vv[i] - hf);
        hv[i] = (short)hb;
        lv[i] = (short)lb;
    }
    *(short8*)(eh + base) = hv;
    *(short8*)(el + base) = lv;
}

// ---------------------------------------------------------------------------
// MFMA distance GEMM v7: score = -2*(zh.eh + zh.el + zl.eh)
// Slab-resident B: per 64-code slab, the FULL 256-k B panel (64 KB, h+l) is
// staged once into LDS; then 8 K-steps (384 MFMA/wave) run with NO barriers
// inside (compiler software-pipelines A loads + ds_reads across the window).
// 2 barriers per ~7500-cyc slab window vs v4's 2 per 340 cyc.
// A loaded direct from global in fragment layout (v5/v6-proven), L2-hot via
// ng-fastest ordering (8 consecutive blocks share the A panel).
// Block = 256 rows x 1024 codes; wave = 64 rows x 64 codes (4mi x 4ni):
// B-fragment reuse x4 -> LDS reads/MFMA = 0.167 (half of v4).
// Each row owned by one wave -> cand written directly (no LDS merge).
// Per-acc MFMA chain order identical to v3/v4 -> bit-identical scores.
// grid 1024 (ng=bid&7, mt=bid>>3). launch_bounds (256,2): no spill.
// ---------------------------------------------------------------------------
__global__ __launch_bounds__(256, 2) void k_gemm(const unsigned short* __restrict__ zh,
                                                 const unsigned short* __restrict__ zl,
                                                 const unsigned short* __restrict__ eh,
                                                 const unsigned short* __restrict__ el,
                                                 u64* __restrict__ cand) {
    // Bs[arr][tile][slot]: arr 0=eh 1=el; tile tau = ni*8+kc (16 codes x 32 k);
    // slot l (16B) holds (code = l&15, k-chunk = l>>4). 64 KB total.
    __shared__ __align__(16) unsigned short Bs[2][32][512];

    int tid  = threadIdx.x;
    int w    = tid >> 6;
    int lane = tid & 63;
    int lm   = lane & 15;
    int q    = lane >> 4;

    int bid = blockIdx.x;
    int ng  = bid & 7;              // fastest: 8 consecutive blocks share mt's A
    int mt  = bid >> 3;

    // A direct-load bases (per-lane fragment addressing, v5/v6-proven):
    // global row = mt*256 + w*64 + mi*16 + lm ; k = q*8 + kc*32
    const unsigned short* Ahw = zh + (size_t)(mt * 256 + w * 64 + lm) * 256 + q * 8;
    const unsigned short* Alw = zl + (size_t)(mt * 256 + w * 64 + lm) * 256 + q * 8;

    // stage assignment: wave w covers (arr = w>>1, tiles st0..st0+15)
    int sarr = w >> 1;
    int st0  = (w & 1) * 16;
    const unsigned short* sgb = (sarr ? el : eh);
    int scode = lane & 15;          // code within tile
    int sk    = (lane >> 4) * 8;    // k-chunk within tile

    // float-domain top-2 per (mi,reg): track MAX of acc (score = -2*acc).
    float v1a[4][4], v2a[4][4];
    int   i1a[4][4], i2a[4][4];
#pragma unroll
    for (int mi = 0; mi < 4; mi++)
#pragma unroll
        for (int reg = 0; reg < 4; reg++) {
            v1a[mi][reg] = -3.4e38f; v2a[mi][reg] = -3.4e38f;
            i1a[mi][reg] = 0;        i2a[mi][reg] = 0;
        }

    f32x4 acc[4][4];

    for (int ns = 0; ns < 16; ++ns) {
        if (ns) __syncthreads();        // prior slab's readers done
        {   // stage this slab's full B panel (64 codes x 256 k, h+l)
            int cbase = ng * 1024 + ns * 64;
#pragma unroll
            for (int i = 0; i < 16; i++) {
                int tau  = st0 + i;
                int code = cbase + (tau >> 3) * 16 + scode;
                int k    = (tau & 7) * 32 + sk;
                async_copy16(&Bs[sarr][tau][0], sgb + (size_t)code * 256 + k);
            }
        }
        __syncthreads();                // stage complete (drains vmcnt)

#pragma unroll
        for (int mi = 0; mi < 4; mi++)
#pragma unroll
            for (int ni = 0; ni < 4; ni++) acc[mi][ni] = (f32x4){0.f, 0.f, 0.f, 0.f};

        __builtin_amdgcn_s_setprio(1);
#pragma unroll 2
        for (int kc = 0; kc < 8; ++kc) {
            int koff = kc * 32;
            short8 fah[4], fal[4];
#pragma unroll
            for (int mi = 0; mi < 4; mi++) {
                fah[mi] = *(const short8*)(Ahw + mi * 4096 + koff);
                fal[mi] = *(const short8*)(Alw + mi * 4096 + koff);
            }
#pragma unroll
            for (int ni = 0; ni < 4; ni++) {
                short8 bh = *(const short8*)&Bs[0][ni * 8 + kc][lane * 8];
                short8 bl = *(const short8*)&Bs[1][ni * 8 + kc][lane * 8];
#pragma unroll
                for (int mi = 0; mi < 4; mi++) {
                    acc[mi][ni] = __builtin_amdgcn_mfma_f32_16x16x32_bf16(fah[mi], bh, acc[mi][ni], 0, 0, 0);
                    acc[mi][ni] = __builtin_amdgcn_mfma_f32_16x16x32_bf16(fal[mi], bh, acc[mi][ni], 0, 0, 0);
                    acc[mi][ni] = __builtin_amdgcn_mfma_f32_16x16x32_bf16(fah[mi], bl, acc[mi][ni], 0, 0, 0);
                }
            }
        }
        __builtin_amdgcn_s_setprio(0);

        // fold slab into per-lane top-2 (codes ascending: ns outer, ni inner)
        int idb = ng * 1024 + ns * 64 + lm;
#pragma unroll
        for (int ni = 0; ni < 4; ni++) {
            int id = idb + ni * 16;
#pragma unroll
            for (int mi = 0; mi < 4; mi++)
#pragma unroll
                for (int reg = 0; reg < 4; reg++) {
                    float v = acc[mi][ni][reg];
                    bool c2 = v > v2a[mi][reg];
                    bool c1 = v > v1a[mi][reg];
                    v2a[mi][reg] = c2 ? v  : v2a[mi][reg];
                    i2a[mi][reg] = c2 ? id : i2a[mi][reg];
                    v2a[mi][reg] = c1 ? v1a[mi][reg] : v2a[mi][reg];
                    i2a[mi][reg] = c1 ? i1a[mi][reg] : i2a[mi][reg];
                    v1a[mi][reg] = c1 ? v  : v1a[mi][reg];
                    i1a[mi][reg] = c1 ? id : i1a[mi][reg];
                }
        }
    }

    // pack to mapf-u64, butterfly across the 16 lm-lanes; each wave owns its
    // 64 rows exclusively -> write cand directly (no LDS merge, no barrier).
#pragma unroll
    for (int mi = 0; mi < 4; mi++)
#pragma unroll
        for (int reg = 0; reg < 4; reg++) {
            float s1 = -2.0f * v1a[mi][reg];
            float s2 = -2.0f * v2a[mi][reg];
            u64 p1 = ((u64)mapf(s1) << 32) | (unsigned)i1a[mi][reg];
            u64 p2 = ((u64)mapf(s2) << 32) | (unsigned)i2a[mi][reg];
#pragma unroll
            for (int msk = 1; msk <= 8; msk <<= 1) {
                u64 q1 = __shfl_xor(p1, msk, 64);
                u64 q2 = __shfl_xor(p2, msk, 64);
                u64 n1 = (p1 < q1) ? p1 : q1;
                u64 hi = (p1 < q1) ? q1 : p1;
                u64 n2 = (q2 < p2) ? q2 : p2;
                n2 = (hi < n2) ? hi : n2;
                p1 = n1; p2 = n2;
            }
            if (lm == 0) {
                int m = mt * 256 + w * 64 + mi * 16 + q * 4 + reg;  // global row
                size_t o = ((size_t)ng * 32768 + m) * 2;
                cand[o]     = p1;
                cand[o + 1] = p2;
            }
        }
}

// ---------------------------------------------------------------------------
// select (MFMA path): merge 8 (top1,top2) pairs; commit or flag. grid 128
// ---------------------------------------------------------------------------
__global__ __launch_bounds__(256) void k_select(const u64* __restrict__ cand,
                                                const float* __restrict__ A32,
                                                int* __restrict__ keys,
                                                int* __restrict__ cnt,
                                                int* __restrict__ list) {
    int n = blockIdx.x * 256 + threadIdx.x;
    u64 m1 = cand[(size_t)n * 2];
    u64 m2 = cand[(size_t)n * 2 + 1];
#pragma unroll
    for (int j = 1; j < 8; j++) {
        u64 c1 = cand[((size_t)j * 32768 + n) * 2];
        u64 c2 = cand[((size_t)j * 32768 + n) * 2 + 1];
        if (c1 < m1) { m2 = (m1 < m2) ? m1 : m2; m1 = c1; }
        else         { m2 = (c1 < m2) ? c1 : m2; }
        m2 = (c2 < m2) ? c2 : m2;
    }
    keys[n] = (int)(unsigned)(m1 & 0xFFFFFFFFull);
    float f1 = unmapf((unsigned)(m1 >> 32));
    float f2 = unmapf((unsigned)(m2 >> 32));
    float W = ((A32[n] >= 255.9f) ? 3.4e-5f : 1.8e-5f) + 4e-6f;  // + 2*eps(bf16x3)
    if (f2 - f1 <= W) {
        int p = atomicAdd(cnt, 1);
        list[p] = n;
    }
}

// ---------------------------------------------------------------------------
// FALLBACK path (round-3 proven): fp32 VALU GEMM argmin + its select
// ---------------------------------------------------------------------------
__global__ __launch_bounds__(256) void k_argmin_fb(const float* __restrict__ z,
                                                   const float* __restrict__ emb,
                                                   u64* __restrict__ cand2) {
    __shared__ __align__(16) float smem[8192];
    float* As = smem;
    float* Bs = smem + 4096;

    int tid = threadIdx.x;
    int tx  = tid & 15;
    int ty  = tid >> 4;
    int mt  = blockIdx.x;
    int kh  = blockIdx.y;

    int bimg = mt >> 4;
    int t0   = (mt & 15) << 7;
    const float* zb = z + (size_t)bimg * (DD * TT) + t0;

    float bestv[8], bestv2[8];
    int   besti[8];
#pragma unroll
    for (int i = 0; i < 8; i++) { bestv[i] = 3.4e38f; bestv2[i] = 3.4e38f; besti[i] = 0; }

    int qa = tid & 31, ra = tid >> 5;
    int jb = tid >> 3, db = tid & 7;
    int swz_t = (tx & 7) << 2;

    for (int kc = 0; kc < 32; kc++) {
        int k0 = kh * 4096 + kc * 128;
        float acc[8][8];
#pragma unroll
        for (int i = 0; i < 8; i++)
#pragma unroll
            for (int j = 0; j < 8; j++) acc[i][j] = 0.0f;

        for (int dc = 0; dc < 8; dc++) {
            int d0 = dc * 32;
            __syncthreads();
#pragma unroll
            for (int s = 0; s < 4; s++) {
                int d = ra + 8 * s;
                float4 v = *(const float4*)(zb + (size_t)(d0 + d) * TT + 4 * qa);
                *(float4*)(As + d * 128 + 4 * qa) = v;
            }
#pragma unroll
            for (int s = 0; s < 4; s++) {
                int row = jb + 32 * s;
                float4 v = *(const float4*)(emb + (size_t)(k0 + row) * DD + d0 + 4 * db);
                int col  = (4 * db) ^ ((row & 7) << 2);
                *(float4*)(Bs + row * 32 + col) = v;
            }
            __syncthreads();
#pragma unroll
            for (int g = 0; g < 8; g++) {
                float4 bf[8];
#pragma unroll
                for (int in = 0; in < 8; in++) {
                    int nn = in * 16 + tx;
                    bf[in] = *(const float4*)(Bs + nn * 32 + ((4 * g) ^ swz_t));
                }
#pragma unroll
                for (int j = 0; j < 4; j++) {
                    int d = 4 * g + j;
                    float4 a0 = *(const float4*)(As + d * 128 + ty * 8);
                    float4 a1 = *(const float4*)(As + d * 128 + ty * 8 + 4);
                    float av[8] = {a0.x, a0.y, a0.z, a0.w, a1.x, a1.y, a1.z, a1.w};
#pragma unroll
                    for (int im = 0; im < 8; im++) {
#pragma unroll
                        for (int in = 0; in < 8; in++) {
                            const float* bfp = (const float*)&bf[in];
                            acc[im][in] = fmaf(av[im], bfp[j], acc[im][in]);
                        }
                    }
                }
            }
        }
#pragma unroll
        for (int in = 0; in < 8; in++) {
            int k = k0 + in * 16 + tx;
#pragma unroll
            for (int im = 0; im < 8; im++) {
                float s = -2.0f * acc[im][in];
                if (s < bestv[im]) { bestv2[im] = bestv[im]; bestv[im] = s; besti[im] = k; }
                else if (s < bestv2[im]) { bestv2[im] = s; }
            }
        }
    }

    __syncthreads();
    u64* red = (u64*)smem;
#pragma unroll
    for (int im = 0; im < 8; im++) {
        int r = ty * 8 + im;
        red[r * 32 + tx * 2 + 0] = ((u64)mapf(bestv[im]) << 32) | (unsigned)besti[im];
        red[r * 32 + tx * 2 + 1] = ((u64)mapf(bestv2[im]) << 32);
    }
    __syncthreads();
    if (tid < 128) {
        const u64* base = red + tid * 32;
        u64 p1 = base[0];
        u64 s2 = base[1];
#pragma unroll
        for (int t = 1; t < 16; t++) {
            u64 c1 = base[t * 2], c2 = base[t * 2 + 1];
            if (c1 < p1) { s2 = (p1 < s2) ? p1 : s2; p1 = c1; }
            else         { s2 = (c1 < s2) ? c1 : s2; }
            s2 = (c2 < s2) ? c2 : s2;
        }
        int n = mt * 128 + tid;
        cand2[(size_t)n * 4 + kh * 2]     = p1;
        cand2[(size_t)n * 4 + kh * 2 + 1] = s2;
    }
}

__global__ __launch_bounds__(256) void k_select_fb(const u64* __restrict__ cand2,
                                                   const float* __restrict__ A32,
                                                   int* __restrict__ keys,
                                                   int* __restrict__ cnt,
                                                   int* __restrict__ list) {
    int n = blockIdx.x * 256 + threadIdx.x;
    u64 a1 = cand2[(size_t)n * 4 + 0], a2 = cand2[(size_t)n * 4 + 1];
    u64 b1 = cand2[(size_t)n * 4 + 2], b2 = cand2[(size_t)n * 4 + 3];
    u64 m1 = (a1 < b1) ? a1 : b1;
    u64 lo = (a1 < b1) ? b1 : a1;
    u64 m2 = (a2 < b2) ? a2 : b2;
    m2 = (lo < m2) ? lo : m2;

    keys[n] = (int)(unsigned)(m1 & 0xFFFFFFFFull);
    float f1 = unmapf((unsigned)(m1 >> 32));
    float f2 = unmapf((unsigned)(m2 >> 32));
    float W = (A32[n] >= 255.9f) ? 3.4e-5f : 1.8e-5f;
    if (f2 - f1 <= W) {
        int p = atomicAdd(cnt, 1);
        list[p] = n;
    }
}

// ---------------------------------------------------------------------------
// exact np-fp32 emulation for flagged rows (round-3 proven). grid 512
// ---------------------------------------------------------------------------
__global__ __launch_bounds__(256) void k_refine(const float* __restrict__ z,
                                                const float* __restrict__ emb,
                                                const float* __restrict__ A32,
                                                const int* __restrict__ list,
                                                const int* __restrict__ cnt,
                                                int* __restrict__ keys) {
    __shared__ __align__(16) float zs[256][8];
    __shared__ float aA[8];
    __shared__ int   ln[8];
    __shared__ u64   wred[4 * 8];

    int tid = threadIdx.x, lane = tid & 63, w = tid >> 6;
    int count = *cnt;
    int ngroups = (count + 7) >> 3;

    for (int g = blockIdx.x; g < ngroups; g += gridDim.x) {
        __syncthreads();
#pragma unroll
        for (int r = 0; r < 8; r++) {
            int row = g * 8 + r;
            int n   = list[(row < count) ? row : 0];
            int b = n >> 11, t = n & 2047;
            zs[tid][r] = z[(size_t)b * (DD * TT) + (size_t)tid * TT + t];
            if (tid == 0) { ln[r] = (row < count) ? n : -1; aA[r] = A32[n]; }
        }
        __syncthreads();

        u64 best[8];
#pragma unroll
        for (int r = 0; r < 8; r++) best[r] = 0xFFFFFFFFFFFFFFFFull;

        float Ar[8];
#pragma unroll
        for (int r = 0; r < 8; r++) Ar[r] = aA[r];

        for (int c = 0; c < 8; c++) {
            int kbase = c * 1024 + tid;
            const float4* e0 = (const float4*)(emb + (size_t)(kbase)       * DD);
            const float4* e1 = (const float4*)(emb + (size_t)(kbase + 256) * DD);
            const float4* e2 = (const float4*)(emb + (size_t)(kbase + 512) * DD);
            const float4* e3 = (const float4*)(emb + (size_t)(kbase + 768) * DD);
            float acc[4][8];
#pragma unroll
            for (int qq = 0; qq < 4; qq++)
#pragma unroll
                for (int r = 0; r < 8; r++) acc[qq][r] = 0.0f;

            for (int d4 = 0; d4 < 64; d4++) {
                float4 v0 = e0[d4], v1 = e1[d4], v2 = e2[d4], v3 = e3[d4];
                const float* p0 = (const float*)&v0;
                const float* p1 = (const float*)&v1;
                const float* p2 = (const float*)&v2;
                const float* p3 = (const float*)&v3;
#pragma unroll
                for (int i = 0; i < 4; i++) {
                    int d = 4 * d4 + i;
                    float4 za = *(const float4*)&zs[d][0];
                    float4 zb2 = *(const float4*)&zs[d][4];
                    const float* zr  = (const float*)&za;
                    const float* zr2 = (const float*)&zb2;
#pragma unroll
                    for (int r = 0; r < 4; r++) {
                        acc[0][r]     = fmaf(zr[r],  p0[i], acc[0][r]);
                        acc[1][r]     = fmaf(zr[r],  p1[i], acc[1][r]);
                        acc[2][r]     = fmaf(zr[r],  p2[i], acc[2][r]);
                        acc[3][r]     = fmaf(zr[r],  p3[i], acc[3][r]);
                        acc[0][r + 4] = fmaf(zr2[r], p0[i], acc[0][r + 4]);
                        acc[1][r + 4] = fmaf(zr2[r], p1[i], acc[1][r + 4]);
                        acc[2][r + 4] = fmaf(zr2[r], p2[i], acc[2][r + 4]);
                        acc[3][r + 4] = fmaf(zr2[r], p3[i], acc[3][r + 4]);
                    }
                }
            }
#pragma unroll
            for (int qq = 0; qq < 4; qq++) {
                int k = kbase + qq * 256;
#pragma unroll
                for (int r = 0; r < 8; r++) {
                    float dk = Ar[r] - 2.0f * acc[qq][r];
                    u64 p = ((u64)mapf(dk) << 32) | (unsigned)k;
                    best[r] = (p < best[r]) ? p : best[r];
                }
            }
        }
#pragma unroll
        for (int r = 0; r < 8; r++) {
            u64 v = best[r];
            for (int off = 32; off; off >>= 1) {
                u64 o = __shfl_down(v, off, 64);
                v = (o < v) ? o : v;
            }
            if (lane == 0) wred[w * 8 + r] = v;
        }
        __syncthreads();
        if (tid < 8) {
            u64 v = wred[tid];
#pragma unroll
            for (int j = 1; j < 4; j++) {
                u64 o = wred[j * 8 + tid];
                v = (o < v) ? o : v;
            }
            int n = ln[tid];
            if (n >= 0) keys[n] = (int)(unsigned)(v & 0xFFFFFFFFull);
        }
        __syncthreads();
    }
}

// ---------------------------------------------------------------------------
// gather quantized, write outputs, loss = 1.25 * mean((q - z)^2)
// ---------------------------------------------------------------------------
__global__ __launch_bounds__(256) void k_out(const float* __restrict__ z,
                                             const float* __restrict__ emb,
                                             const int* __restrict__ keys,
                                             float* __restrict__ out) {
    int tid = threadIdx.x;
    int n   = blockIdx.x * 256 + tid;
    int b   = n >> 11;
    int t   = n & 2047;
    int idx = keys[n];
    out[QQ + 1 + n] = (float)idx;

    const float4* erow = (const float4*)(emb + (size_t)idx * DD);
    const float*  zp   = z   + (size_t)b * (DD * TT) + t;
    float*        op   = out + (size_t)b * (DD * TT) + t;

    float ssd = 0.0f;
#pragma unroll 4
    for (int d4 = 0; d4 < 64; d4++) {
        float4 qv = erow[d4];
        float qa[4] = {qv.x, qv.y, qv.z, qv.w};
#pragma unroll
        for (int r = 0; r < 4; r++) {
            int d = 4 * d4 + r;
            float zv = zp[(size_t)d * TT];
            float df = qa[r] - zv;
            ssd = fmaf(df, df, ssd);
            op[(size_t)d * TT] = qa[r];
        }
    }
    for (int off = 32; off; off >>= 1) ssd += __shfl_down(ssd, off, 64);
    __shared__ float red[4];
    if ((tid & 63) == 0) red[tid >> 6] = ssd;
    __syncthreads();
    if (tid == 0) {
        float tot = red[0] + red[1] + red[2] + red[3];
        atomicAdd(out + QQ, tot * (1.25f / (float)QQ));
    }
}

// ---------------------------------------------------------------------------
extern "C" void kernel_launch(void* const* d_in, const int* in_sizes, int n_in,
                              void* d_out, int out_size, void* d_ws, size_t ws_size,
                              hipStream_t stream) {
    const float* z   = (const float*)d_in[0];   // [16, 256, 2048]
    const float* emb = (const float*)d_in[1];   // [8192, 256]
    float* out = (float*)d_out;

    char* ws = (char*)d_ws;
    const size_t oZH = 0;
    const size_t oZL = oZH + 16777216;
    const size_t oEH = oZL + 16777216;
    const size_t oEL = oEH + 4194304;
    const size_t oCD = oEL + 4194304;          // cand: 8*32768*2*8 = 4 MB
    const size_t oA3 = oCD + 4194304;
    const size_t oKY = oA3 + 131072;
    const size_t oLS = oKY + 131072;
    const size_t oCN = oLS + 131072;
    const size_t needed = oCN + 64;

    if (ws_size >= needed) {
        unsigned short* zh = (unsigned short*)(ws + oZH);
        unsigned short* zl = (unsigned short*)(ws + oZL);
        unsigned short* eh = (unsigned short*)(ws + oEH);
        unsigned short* el = (unsigned short*)(ws + oEL);
        u64*   cand = (u64*)(ws + oCD);
        float* A32  = (float*)(ws + oA3);
        int*   keys = (int*)(ws + oKY);
        int*   list = (int*)(ws + oLS);
        int*   cnt  = (int*)(ws + oCN);

        k_prepA <<<512,  256, 0, stream>>>(z, A32, cnt, out);
        k_convZ <<<2048, 256, 0, stream>>>(z, zh, zl);
        k_convE <<<1024, 256, 0, stream>>>(emb, eh, el);
        k_gemm  <<<1024, 256, 0, stream>>>(zh, zl, eh, el, cand);
        k_select<<<128,  256, 0, stream>>>(cand, A32, keys, cnt, list);
        k_refine<<<512,  256, 0, stream>>>(z, emb, A32, list, cnt, keys);
        k_out   <<<128,  256, 0, stream>>>(z, emb, keys, out);
    } else {
        // fallback: round-3 proven path (~1.5 MB ws)
        u64*   cand2 = (u64*)ws;                          // 1 MB
        float* A32   = (float*)(ws + 1048576);            // 128 KB
        int*   keys  = (int*)(ws + 1048576 + 131072);
        int*   list  = (int*)(ws + 1048576 + 262144);
        int*   cnt   = (int*)(ws + 1048576 + 393216);

        k_prepA    <<<512,          256, 0, stream>>>(z, A32, cnt, out);
        k_argmin_fb<<<dim3(256, 2), 256, 0, stream>>>(z, emb, cand2);
        k_select_fb<<<128,          256, 0, stream>>>(cand2, A32, keys, cnt, list);
        k_refine   <<<512,          256, 0, stream>>>(z, emb, A32, list, cnt, keys);
        k_out      <<<128,          256, 0, stream>>>(z, emb, keys, out);
    }
}

// Round 6
// 950.485 us; speedup vs baseline: 1.9571x; 1.4355x over previous
//
#include <hip/hip_runtime.h>
#include <cstdint>

#define BB 16
#define DD 256
#define TT 2048
#define KK 8192
#define NN 32768            // BB*TT
#define QQ 8388608          // BB*DD*TT
typedef unsigned long long u64;

typedef __attribute__((ext_vector_type(8))) short short8;   // 8 bf16 (4 VGPRs)
typedef __attribute__((ext_vector_type(4))) float f32x4;    // MFMA C/D

#define GLOBAL_AS __attribute__((address_space(1)))
#define LDS_AS    __attribute__((address_space(3)))

// async global->LDS, 16 B per lane; LDS dest = wave-uniform base + lane*16
__device__ __forceinline__ void async_copy16(void* l, const void* g) {
    __builtin_amdgcn_global_load_lds((const GLOBAL_AS unsigned int*)g,
                                     (LDS_AS unsigned int*)l, 16, 0, 0);
}

__device__ __forceinline__ unsigned mapf(float f) {
    unsigned u = __float_as_uint(f);
    return (u & 0x80000000u) ? ~u : (u | 0x80000000u);
}
__device__ __forceinline__ float unmapf(unsigned u) {
    return __uint_as_float((u & 0x80000000u) ? (u & 0x7FFFFFFFu) : ~u);
}
__device__ __forceinline__ unsigned bf16_rne(float v) {
    unsigned ui = __float_as_uint(v);
    return (ui + 0x7FFFu + ((ui >> 16) & 1)) >> 16;
}

// ---------------------------------------------------------------------------
// A32[n] = fp32(fp64 sum of z_n^2); zero cnt & loss. grid 512 x 256
// ---------------------------------------------------------------------------
__global__ __launch_bounds__(256) void k_prepA(const float* __restrict__ z,
                                               float* __restrict__ A32,
                                               int* __restrict__ cnt,
                                               float* __restrict__ out) {
    __shared__ double sd[256];
    int tid = threadIdx.x;
    int r = tid & 63;               // row within block (coalesced over t)
    int c = tid >> 6;               // wave -> d quarter
    int n = blockIdx.x * 64 + r;
    if (blockIdx.x == 0 && tid == 0) { *cnt = 0; out[QQ] = 0.0f; }
    int b = n >> 11, t = n & 2047;
    const float* zp = z + (size_t)b * 524288 + t;
    double s = 0.0;
#pragma unroll 8
    for (int i = 0; i < 64; i++) {
        float v = zp[(size_t)(c * 64 + i) * 2048];
        s = fma((double)v, (double)v, s);
    }
    sd[tid] = s;
    __syncthreads();
    if (c == 0) {
        double tot = sd[r] + sd[64 + r] + sd[128 + r] + sd[192 + r];
        A32[n] = (float)tot;
    }
}

// ---------------------------------------------------------------------------
// z [b][d][t] fp32 -> zh/zl [n][d] bf16 hi/lo, 16B stores. grid 2048 x 256
// ---------------------------------------------------------------------------
__global__ __launch_bounds__(256) void k_convZ(const float* __restrict__ z,
                                               unsigned short* __restrict__ zh,
                                               unsigned short* __restrict__ zl) {
    __shared__ float sm[64][65];
    int tid = threadIdx.x;
    int bid = blockIdx.x;
    int b  = bid >> 7;
    int dt = (bid >> 5) & 3;
    int tt = bid & 31;
    const float* zp = z + (size_t)b * 524288 + (size_t)dt * 131072 + tt * 64;
#pragma unroll
    for (int i = 0; i < 16; i++) {
        int idx = tid + 256 * i;
        int d = idx >> 6, t = idx & 63;
        sm[d][t] = zp[(size_t)d * 2048 + t];
    }
    __syncthreads();
    int d0 = (tid & 7) * 8;
#pragma unroll
    for (int i = 0; i < 2; i++) {
        int t = (tid >> 3) + 32 * i;
        size_t o = ((size_t)(b * 2048 + tt * 64 + t)) * 256 + dt * 64 + d0;
        short8 hv, lv;
#pragma unroll
        for (int j = 0; j < 8; j++) {
            float v = sm[d0 + j][t];
            unsigned hb = bf16_rne(v);
            float hf = __uint_as_float(hb << 16);
            unsigned lb = bf16_rne(v - hf);
            hv[j] = (short)hb;
            lv[j] = (short)lb;
        }
        *(short8*)(zh + o) = hv;
        *(short8*)(zl + o) = lv;
    }
}

// ---------------------------------------------------------------------------
// emb [k][d] fp32 -> eh/el bf16 hi/lo. grid 1024 x 256
// ---------------------------------------------------------------------------
__global__ __launch_bounds__(256) void k_convE(const float* __restrict__ emb,
                                               unsigned short* __restrict__ eh,
                                               unsigned short* __restrict__ el) {
    int base = (blockIdx.x * 256 + threadIdx.x) * 8;
    float4 v0 = *(const float4*)(emb + base);
    float4 v1 = *(const float4*)(emb + base + 4);
    float vv[8] = {v0.x, v0.y, v0.z, v0.w, v1.x, v1.y, v1.z, v1.w};
    short8 hv, lv;
#pragma unroll
    for (int i = 0; i < 8; i++) {
        unsigned hb = bf16_rne(vv[i]);
        float hf = __uint_as_float(hb << 16);
        unsigned lb = bf16_rne(vv[i] - hf);
        hv[i] = (short)hb;
        lv[i] = (short)lb;
    }
    *(short8*)(eh + base) = hv;
    *(short8*)(el + base) = lv;
}

// ---------------------------------------------------------------------------
// MFMA distance GEMM v8: score = -2*(zh.eh + zh.el + zl.eh)
// 256-row x 1024-code block (4 passes of 256 codes), 512 threads = 8 waves
// (4 row-groups x 2 code-halves), wave tile 64x128 (4mi x 8ni): 24 ds_reads
// per 96 MFMA (4 MFMA/read vs v4's 3), staging per MFMA halved. All four
// sources LDS-staged (v5/v6/v7 proved direct-global A fails), BK=32,
// double-buffered 128 KB LDS, 1 block/CU. SINGLE barrier per K-step:
// vmcnt(0)+barrier at top (loads issued one full compute-window earlier ->
// drain is free), stage issued AFTER the barrier into the non-read buffer.
// XCD-chunked tile swizzle (bijective, 1024%8==0). Top-2 fold tracks value
// only for #2 (k_select never reads i2). Per-acc MFMA chain order and k-order
// identical to v3/v4 -> bit-identical scores -> select/refine contract holds.
// grid 1024 (tl = (bid&7)*128 + bid>>3; mt = tl>>3, ng = tl&7).
// ---------------------------------------------------------------------------
__global__ __launch_bounds__(512, 2) void k_gemm(const unsigned short* __restrict__ zh,
                                                 const unsigned short* __restrict__ zl,
                                                 const unsigned short* __restrict__ eh,
                                                 const unsigned short* __restrict__ el,
                                                 u64* __restrict__ cand) {
    // per buffer (64 KB): zh tiles [0,8192), zl [8192,16384), eh [16384,24576),
    // el [24576,32768) shorts; tile = 16 rows x 32 k = 512 shorts, fragment-
    // major (slot l = 16B: row = l&15, k-chunk = l>>4). rtop (8 KB) aliases
    // pool[0] after the final barrier.
    __shared__ __align__(16) unsigned short pool[2][32768];   // 128 KB

    int tid  = threadIdx.x;
    int w    = __builtin_amdgcn_readfirstlane(tid >> 6);   // wave id (uniform)
    int lane = tid & 63;
    int lm   = lane & 15;
    int q    = lane >> 4;
    int wm   = w >> 1;              // 0..3: 64-row group
    int wn   = w & 1;               // 0..1: 128-code half

    int bid = blockIdx.x;
    int tl  = (bid & 7) * 128 + (bid >> 3);   // XCD-chunked (1024 % 8 == 0)
    int mt  = tl >> 3;              // 0..127: 256-row tile
    int ng  = tl & 7;               // 0..7  : 1024-code group

    // ---- staging: 8 copies/wave; slot = w*8+i -> (arr = slot>>4, tile = slot&15)
    int laneoff = lm * 256 + q * 8;          // per-lane (row, k-chunk) offset
    const unsigned short* gp[8];
    unsigned dlo[8];
    bool bflag[8];
#pragma unroll
    for (int i = 0; i < 8; i++) {
        int slot = w * 8 + i;
        int arr  = slot >> 4;
        int tile = slot & 15;
        const unsigned short* s = (arr == 0) ? zh : (arr == 1) ? zl
                                : (arr == 2) ? eh : el;
        int rowb = (arr < 2) ? mt * 256 : ng * 1024;
        gp[i]    = s + (size_t)(rowb + tile * 16) * 256 + laneoff;
        dlo[i]   = (unsigned)(arr * 8192 + tile * 512);
        bflag[i] = (arr >= 2);
    }

    // float-domain top-2 per (mi,reg): track MAX of acc (score = -2*acc).
    // #2 index never used downstream -> value-only for #2.
    float v1a[4][4], v2a[4][4];
    int   i1a[4][4];
#pragma unroll
    for (int mi = 0; mi < 4; mi++)
#pragma unroll
        for (int reg = 0; reg < 4; reg++) {
            v1a[mi][reg] = -3.4e38f; v2a[mi][reg] = -3.4e38f;
            i1a[mi][reg] = 0;
        }

    f32x4 acc[4][8];

    // prologue: stage k-tile 0 into buffer 0
#pragma unroll
    for (int i = 0; i < 8; i++)
        async_copy16(&pool[0][dlo[i]], gp[i]);

    for (int t = 0; t < 32; ++t) {            // 4 passes x 8 K-steps
        int buf = t & 1;
        int kc  = t & 7;

        // stage(t) was issued one full compute window ago -> drain is free
        asm volatile("s_waitcnt vmcnt(0)" ::: "memory");
        __builtin_amdgcn_s_barrier();          // buf complete + prior readers done
        __builtin_amdgcn_sched_barrier(0);

        int tn = t + 1;
        if (tn < 32) {
            if ((tn & 7) == 0) {               // next stage starts a new 256-code pass
#pragma unroll
                for (int i = 0; i < 8; i++)
                    if (bflag[i]) gp[i] += 65536;   // +256 codes
            }
            int nkc = tn & 7;
#pragma unroll
            for (int i = 0; i < 8; i++)
                async_copy16(&pool[buf ^ 1][dlo[i]], gp[i] + nkc * 32);
        }

        if (kc == 0) {
#pragma unroll
            for (int mi = 0; mi < 4; mi++)
#pragma unroll
                for (int ni = 0; ni < 8; ni++) acc[mi][ni] = (f32x4){0.f, 0.f, 0.f, 0.f};
        }

        const unsigned short* pb = pool[buf];
        short8 azh[4], azl[4];
#pragma unroll
        for (int mi = 0; mi < 4; mi++) {
            azh[mi] = *(const short8*)&pb[(wm * 4 + mi) * 512 + lane * 8];
            azl[mi] = *(const short8*)&pb[8192 + (wm * 4 + mi) * 512 + lane * 8];
        }
        __builtin_amdgcn_s_setprio(1);
#pragma unroll
        for (int ni = 0; ni < 8; ni++) {
            short8 bh = *(const short8*)&pb[16384 + (wn * 8 + ni) * 512 + lane * 8];
            short8 bl = *(const short8*)&pb[24576 + (wn * 8 + ni) * 512 + lane * 8];
#pragma unroll
            for (int mi = 0; mi < 4; mi++) {
                acc[mi][ni] = __builtin_amdgcn_mfma_f32_16x16x32_bf16(azh[mi], bh, acc[mi][ni], 0, 0, 0);
                acc[mi][ni] = __builtin_amdgcn_mfma_f32_16x16x32_bf16(azl[mi], bh, acc[mi][ni], 0, 0, 0);
                acc[mi][ni] = __builtin_amdgcn_mfma_f32_16x16x32_bf16(azh[mi], bl, acc[mi][ni], 0, 0, 0);
            }
        }
        __builtin_amdgcn_s_setprio(0);

        if (kc == 7) {   // pass complete: fold 256 codes into per-lane top-2
            int idb = ng * 1024 + (t >> 3) * 256 + wn * 128 + lm;
#pragma unroll
            for (int ni = 0; ni < 8; ni++) {
                int id = idb + ni * 16;
#pragma unroll
                for (int mi = 0; mi < 4; mi++)
#pragma unroll
                    for (int reg = 0; reg < 4; reg++) {
                        float v = acc[mi][ni][reg];
                        bool c1 = v > v1a[mi][reg];
                        bool c2 = v > v2a[mi][reg];
                        v2a[mi][reg] = c2 ? v : v2a[mi][reg];
                        v2a[mi][reg] = c1 ? v1a[mi][reg] : v2a[mi][reg];
                        v1a[mi][reg] = c1 ? v : v1a[mi][reg];
                        i1a[mi][reg] = c1 ? id : i1a[mi][reg];
                    }
            }
        }
        // no end barrier: next iteration's top barrier protects the restage
    }

    // pack to mapf-u64, butterfly across the 16 lm-lanes (bits 0..3 of lane);
    // rtop aliases pool[0] (its last reads were fenced by the t=31 barrier).
    u64* rtop = (u64*)&pool[0][0];
#pragma unroll
    for (int mi = 0; mi < 4; mi++)
#pragma unroll
        for (int reg = 0; reg < 4; reg++) {
            u64 p1 = ((u64)mapf(-2.0f * v1a[mi][reg]) << 32) | (unsigned)i1a[mi][reg];
            u64 p2 = ((u64)mapf(-2.0f * v2a[mi][reg]) << 32);
#pragma unroll
            for (int msk = 1; msk <= 8; msk <<= 1) {
                u64 q1 = __shfl_xor(p1, msk, 64);
                u64 q2 = __shfl_xor(p2, msk, 64);
                u64 n1 = (p1 < q1) ? p1 : q1;
                u64 hi = (p1 < q1) ? q1 : p1;
                u64 n2 = (q2 < p2) ? q2 : p2;
                n2 = (hi < n2) ? hi : n2;
                p1 = n1; p2 = n2;
            }
            if (lm == 0) {
                int rl = wm * 64 + mi * 16 + q * 4 + reg;   // 0..255 block row
                rtop[rl * 4 + wn * 2]     = p1;
                rtop[rl * 4 + wn * 2 + 1] = p2;
            }
        }
    __syncthreads();
    if (tid < 256) {   // merge the two code-halves for each row
        u64 a1 = rtop[tid * 4],     a2 = rtop[tid * 4 + 1];
        u64 b1 = rtop[tid * 4 + 2], b2 = rtop[tid * 4 + 3];
        u64 m1 = (a1 < b1) ? a1 : b1;
        u64 lo = (a1 < b1) ? b1 : a1;
        u64 m2 = (a2 < b2) ? a2 : b2;
        m2 = (lo < m2) ? lo : m2;
        size_t o = ((size_t)ng * 32768 + (size_t)mt * 256 + tid) * 2;
        cand[o]     = m1;
        cand[o + 1] = m2;
    }
}

// ---------------------------------------------------------------------------
// select (MFMA path): merge 8 (top1,top2) pairs; commit or flag. grid 128
// ---------------------------------------------------------------------------
__global__ __launch_bounds__(256) void k_select(const u64* __restrict__ cand,
                                                const float* __restrict__ A32,
                                                int* __restrict__ keys,
                                                int* __restrict__ cnt,
                                                int* __restrict__ list) {
    int n = blockIdx.x * 256 + threadIdx.x;
    u64 m1 = cand[(size_t)n * 2];
    u64 m2 = cand[(size_t)n * 2 + 1];
#pragma unroll
    for (int j = 1; j < 8; j++) {
        u64 c1 = cand[((size_t)j * 32768 + n) * 2];
        u64 c2 = cand[((size_t)j * 32768 + n) * 2 + 1];
        if (c1 < m1) { m2 = (m1 < m2) ? m1 : m2; m1 = c1; }
        else         { m2 = (c1 < m2) ? c1 : m2; }
        m2 = (c2 < m2) ? c2 : m2;
    }
    keys[n] = (int)(unsigned)(m1 & 0xFFFFFFFFull);
    float f1 = unmapf((unsigned)(m1 >> 32));
    float f2 = unmapf((unsigned)(m2 >> 32));
    float W = ((A32[n] >= 255.9f) ? 3.4e-5f : 1.8e-5f) + 4e-6f;  // + 2*eps(bf16x3)
    if (f2 - f1 <= W) {
        int p = atomicAdd(cnt, 1);
        list[p] = n;
    }
}

// ---------------------------------------------------------------------------
// FALLBACK path (round-3 proven): fp32 VALU GEMM argmin + its select
// ---------------------------------------------------------------------------
__global__ __launch_bounds__(256) void k_argmin_fb(const float* __restrict__ z,
                                                   const float* __restrict__ emb,
                                                   u64* __restrict__ cand2) {
    __shared__ __align__(16) float smem[8192];
    float* As = smem;
    float* Bs = smem + 4096;

    int tid = threadIdx.x;
    int tx  = tid & 15;
    int ty  = tid >> 4;
    int mt  = blockIdx.x;
    int kh  = blockIdx.y;

    int bimg = mt >> 4;
    int t0   = (mt & 15) << 7;
    const float* zb = z + (size_t)bimg * (DD * TT) + t0;

    float bestv[8], bestv2[8];
    int   besti[8];
#pragma unroll
    for (int i = 0; i < 8; i++) { bestv[i] = 3.4e38f; bestv2[i] = 3.4e38f; besti[i] = 0; }

    int qa = tid & 31, ra = tid >> 5;
    int jb = tid >> 3, db = tid & 7;
    int swz_t = (tx & 7) << 2;

    for (int kc = 0; kc < 32; kc++) {
        int k0 = kh * 4096 + kc * 128;
        float acc[8][8];
#pragma unroll
        for (int i = 0; i < 8; i++)
#pragma unroll
            for (int j = 0; j < 8; j++) acc[i][j] = 0.0f;

        for (int dc = 0; dc < 8; dc++) {
            int d0 = dc * 32;
            __syncthreads();
#pragma unroll
            for (int s = 0; s < 4; s++) {
                int d = ra + 8 * s;
                float4 v = *(const float4*)(zb + (size_t)(d0 + d) * TT + 4 * qa);
                *(float4*)(As + d * 128 + 4 * qa) = v;
            }
#pragma unroll
            for (int s = 0; s < 4; s++) {
                int row = jb + 32 * s;
                float4 v = *(const float4*)(emb + (size_t)(k0 + row) * DD + d0 + 4 * db);
                int col  = (4 * db) ^ ((row & 7) << 2);
                *(float4*)(Bs + row * 32 + col) = v;
            }
            __syncthreads();
#pragma unroll
            for (int g = 0; g < 8; g++) {
                float4 bf[8];
#pragma unroll
                for (int in = 0; in < 8; in++) {
                    int nn = in * 16 + tx;
                    bf[in] = *(const float4*)(Bs + nn * 32 + ((4 * g) ^ swz_t));
                }
#pragma unroll
                for (int j = 0; j < 4; j++) {
                    int d = 4 * g + j;
                    float4 a0 = *(const float4*)(As + d * 128 + ty * 8);
                    float4 a1 = *(const float4*)(As + d * 128 + ty * 8 + 4);
                    float av[8] = {a0.x, a0.y, a0.z, a0.w, a1.x, a1.y, a1.z, a1.w};
#pragma unroll
                    for (int im = 0; im < 8; im++) {
#pragma unroll
                        for (int in = 0; in < 8; in++) {
                            const float* bfp = (const float*)&bf[in];
                            acc[im][in] = fmaf(av[im], bfp[j], acc[im][in]);
                        }
                    }
                }
            }
        }
#pragma unroll
        for (int in = 0; in < 8; in++) {
            int k = k0 + in * 16 + tx;
#pragma unroll
            for (int im = 0; im < 8; im++) {
                float s = -2.0f * acc[im][in];
                if (s < bestv[im]) { bestv2[im] = bestv[im]; bestv[im] = s; besti[im] = k; }
                else if (s < bestv2[im]) { bestv2[im] = s; }
            }
        }
    }

    __syncthreads();
    u64* red = (u64*)smem;
#pragma unroll
    for (int im = 0; im < 8; im++) {
        int r = ty * 8 + im;
        red[r * 32 + tx * 2 + 0] = ((u64)mapf(bestv[im]) << 32) | (unsigned)besti[im];
        red[r * 32 + tx * 2 + 1] = ((u64)mapf(bestv2[im]) << 32);
    }
    __syncthreads();
    if (tid < 128) {
        const u64* base = red + tid * 32;
        u64 p1 = base[0];
        u64 s2 = base[1];
#pragma unroll
        for (int t = 1; t < 16; t++) {
            u64 c1 = base[t * 2], c2 = base[t * 2 + 1];
            if (c1 < p1) { s2 = (p1 < s2) ? p1 : s2; p1 = c1; }
            else         { s2 = (c1 < s2) ? c1 : s2; }
            s2 = (c2 < s2) ? c2 : s2;
        }
        int n = mt * 128 + tid;
        cand2[(size_t)n * 4 + kh * 2]     = p1;
        cand2[(size_t)n * 4 + kh * 2 + 1] = s2;
    }
}

__global__ __launch_bounds__(256) void k_select_fb(const u64* __restrict__ cand2,
                                                   const float* __restrict__ A32,
                                                   int* __restrict__ keys,
                                                   int* __restrict__ cnt,
                                                   int* __restrict__ list) {
    int n = blockIdx.x * 256 + threadIdx.x;
    u64 a1 = cand2[(size_t)n * 4 + 0], a2 = cand2[(size_t)n * 4 + 1];
    u64 b1 = cand2[(size_t)n * 4 + 2], b2 = cand2[(size_t)n * 4 + 3];
    u64 m1 = (a1 < b1) ? a1 : b1;
    u64 lo = (a1 < b1) ? b1 : a1;
    u64 m2 = (a2 < b2) ? a2 : b2;
    m2 = (lo < m2) ? lo : m2;

    keys[n] = (int)(unsigned)(m1 & 0xFFFFFFFFull);
    float f1 = unmapf((unsigned)(m1 >> 32));
    float f2 = unmapf((unsigned)(m2 >> 32));
    float W = (A32[n] >= 255.9f) ? 3.4e-5f : 1.8e-5f;
    if (f2 - f1 <= W) {
        int p = atomicAdd(cnt, 1);
        list[p] = n;
    }
}

// ---------------------------------------------------------------------------
// exact np-fp32 emulation for flagged rows (round-3 proven). grid 512
// ---------------------------------------------------------------------------
__global__ __launch_bounds__(256) void k_refine(const float* __restrict__ z,
                                                const float* __restrict__ emb,
                                                const float* __restrict__ A32,
                                                const int* __restrict__ list,
                                                const int* __restrict__ cnt,
                                                int* __restrict__ keys) {
    __shared__ __align__(16) float zs[256][8];
    __shared__ float aA[8];
    __shared__ int   ln[8];
    __shared__ u64   wred[4 * 8];

    int tid = threadIdx.x, lane = tid & 63, w = tid >> 6;
    int count = *cnt;
    int ngroups = (count + 7) >> 3;

    for (int g = blockIdx.x; g < ngroups; g += gridDim.x) {
        __syncthreads();
#pragma unroll
        for (int r = 0; r < 8; r++) {
            int row = g * 8 + r;
            int n   = list[(row < count) ? row : 0];
            int b = n >> 11, t = n & 2047;
            zs[tid][r] = z[(size_t)b * (DD * TT) + (size_t)tid * TT + t];
            if (tid == 0) { ln[r] = (row < count) ? n : -1; aA[r] = A32[n]; }
        }
        __syncthreads();

        u64 best[8];
#pragma unroll
        for (int r = 0; r < 8; r++) best[r] = 0xFFFFFFFFFFFFFFFFull;

        float Ar[8];
#pragma unroll
        for (int r = 0; r < 8; r++) Ar[r] = aA[r];

        for (int c = 0; c < 8; c++) {
            int kbase = c * 1024 + tid;
            const float4* e0 = (const float4*)(emb + (size_t)(kbase)       * DD);
            const float4* e1 = (const float4*)(emb + (size_t)(kbase + 256) * DD);
            const float4* e2 = (const float4*)(emb + (size_t)(kbase + 512) * DD);
            const float4* e3 = (const float4*)(emb + (size_t)(kbase + 768) * DD);
            float acc[4][8];
#pragma unroll
            for (int qq = 0; qq < 4; qq++)
#pragma unroll
                for (int r = 0; r < 8; r++) acc[qq][r] = 0.0f;

            for (int d4 = 0; d4 < 64; d4++) {
                float4 v0 = e0[d4], v1 = e1[d4], v2 = e2[d4], v3 = e3[d4];
                const float* p0 = (const float*)&v0;
                const float* p1 = (const float*)&v1;
                const float* p2 = (const float*)&v2;
                const float* p3 = (const float*)&v3;
#pragma unroll
                for (int i = 0; i < 4; i++) {
                    int d = 4 * d4 + i;
                    float4 za = *(const float4*)&zs[d][0];
                    float4 zb2 = *(const float4*)&zs[d][4];
                    const float* zr  = (const float*)&za;
                    const float* zr2 = (const float*)&zb2;
#pragma unroll
                    for (int r = 0; r < 4; r++) {
                        acc[0][r]     = fmaf(zr[r],  p0[i], acc[0][r]);
                        acc[1][r]     = fmaf(zr[r],  p1[i], acc[1][r]);
                        acc[2][r]     = fmaf(zr[r],  p2[i], acc[2][r]);
                        acc[3][r]     = fmaf(zr[r],  p3[i], acc[3][r]);
                        acc[0][r + 4] = fmaf(zr2[r], p0[i], acc[0][r + 4]);
                        acc[1][r + 4] = fmaf(zr2[r], p1[i], acc[1][r + 4]);
                        acc[2][r + 4] = fmaf(zr2[r], p2[i], acc[2][r + 4]);
                        acc[3][r + 4] = fmaf(zr2[r], p3[i], acc[3][r + 4]);
                    }
                }
            }
#pragma unroll
            for (int qq = 0; qq < 4; qq++) {
                int k = kbase + qq * 256;
#pragma unroll
                for (int r = 0; r < 8; r++) {
                    float dk = Ar[r] - 2.0f * acc[qq][r];
                    u64 p = ((u64)mapf(dk) << 32) | (unsigned)k;
                    best[r] = (p < best[r]) ? p : best[r];
                }
            }
        }
#pragma unroll
        for (int r = 0; r < 8; r++) {
            u64 v = best[r];
            for (int off = 32; off; off >>= 1) {
                u64 o = __shfl_down(v, off, 64);
                v = (o < v) ? o : v;
            }
            if (lane == 0) wred[w * 8 + r] = v;
        }
        __syncthreads();
        if (tid < 8) {
            u64 v = wred[tid];
#pragma unroll
            for (int j = 1; j < 4; j++) {
                u64 o = wred[j * 8 + tid];
                v = (o < v) ? o : v;
            }
            int n = ln[tid];
            if (n >= 0) keys[n] = (int)(unsigned)(v & 0xFFFFFFFFull);
        }
        __syncthreads();
    }
}

// ---------------------------------------------------------------------------
// gather quantized, write outputs, loss = 1.25 * mean((q - z)^2)
// ---------------------------------------------------------------------------
__global__ __launch_bounds__(256) void k_out(const float* __restrict__ z,
                                             const float* __restrict__ emb,
                                             const int* __restrict__ keys,
                                             float* __restrict__ out) {
    int tid = threadIdx.x;
    int n   = blockIdx.x * 256 + tid;
    int b   = n >> 11;
    int t   = n & 2047;
    int idx = keys[n];
    out[QQ + 1 + n] = (float)idx;

    const float4* erow = (const float4*)(emb + (size_t)idx * DD);
    const float*  zp   = z   + (size_t)b * (DD * TT) + t;
    float*        op   = out + (size_t)b * (DD * TT) + t;

    float ssd = 0.0f;
#pragma unroll 4
    for (int d4 = 0; d4 < 64; d4++) {
        float4 qv = erow[d4];
        float qa[4] = {qv.x, qv.y, qv.z, qv.w};
#pragma unroll
        for (int r = 0; r < 4; r++) {
            int d = 4 * d4 + r;
            float zv = zp[(size_t)d * TT];
            float df = qa[r] - zv;
            ssd = fmaf(df, df, ssd);
            op[(size_t)d * TT] = qa[r];
        }
    }
    for (int off = 32; off; off >>= 1) ssd += __shfl_down(ssd, off, 64);
    __shared__ float red[4];
    if ((tid & 63) == 0) red[tid >> 6] = ssd;
    __syncthreads();
    if (tid == 0) {
        float tot = red[0] + red[1] + red[2] + red[3];
        atomicAdd(out + QQ, tot * (1.25f / (float)QQ));
    }
}

// ---------------------------------------------------------------------------
extern "C" void kernel_launch(void* const* d_in, const int* in_sizes, int n_in,
                              void* d_out, int out_size, void* d_ws, size_t ws_size,
                              hipStream_t stream) {
    const float* z   = (const float*)d_in[0];   // [16, 256, 2048]
    const float* emb = (const float*)d_in[1];   // [8192, 256]
    float* out = (float*)d_out;

    char* ws = (char*)d_ws;
    const size_t oZH = 0;
    const size_t oZL = oZH + 16777216;
    const size_t oEH = oZL + 16777216;
    const size_t oEL = oEH + 4194304;
    const size_t oCD = oEL + 4194304;          // cand: 8*32768*2*8 = 4 MB
    const size_t oA3 = oCD + 4194304;
    const size_t oKY = oA3 + 131072;
    const size_t oLS = oKY + 131072;
    const size_t oCN = oLS + 131072;
    const size_t needed = oCN + 64;

    if (ws_size >= needed) {
        unsigned short* zh = (unsigned short*)(ws + oZH);
        unsigned short* zl = (unsigned short*)(ws + oZL);
        unsigned short* eh = (unsigned short*)(ws + oEH);
        unsigned short* el = (unsigned short*)(ws + oEL);
        u64*   cand = (u64*)(ws + oCD);
        float* A32  = (float*)(ws + oA3);
        int*   keys = (int*)(ws + oKY);
        int*   list = (int*)(ws + oLS);
        int*   cnt  = (int*)(ws + oCN);

        k_prepA <<<512,  256, 0, stream>>>(z, A32, cnt, out);
        k_convZ <<<2048, 256, 0, stream>>>(z, zh, zl);
        k_convE <<<1024, 256, 0, stream>>>(emb, eh, el);
        k_gemm  <<<1024, 512, 0, stream>>>(zh, zl, eh, el, cand);
        k_select<<<128,  256, 0, stream>>>(cand, A32, keys, cnt, list);
        k_refine<<<512,  256, 0, stream>>>(z, emb, A32, list, cnt, keys);
        k_out   <<<128,  256, 0, stream>>>(z, emb, keys, out);
    } else {
        // fallback: round-3 proven path (~1.5 MB ws)
        u64*   cand2 = (u64*)ws;                          // 1 MB
        float* A32   = (float*)(ws + 1048576);            // 128 KB
        int*   keys  = (int*)(ws + 1048576 + 131072);
        int*   list  = (int*)(ws + 1048576 + 262144);
        int*   cnt   = (int*)(ws + 1048576 + 393216);

        k_prepA    <<<512,          256, 0, stream>>>(z, A32, cnt, out);
        k_argmin_fb<<<dim3(256, 2), 256, 0, stream>>>(z, emb, cand2);
        k_select_fb<<<128,          256, 0, stream>>>(cand2, A32, keys, cnt, list);
        k_refine   <<<512,          256, 0, stream>>>(z, emb, A32, list, cnt, keys);
        k_out      <<<128,          256, 0, stream>>>(z, emb, keys, out);
    }
}